// Round 2
// baseline (1962.235 us; speedup 1.0000x reference)
//
#include <hip/hip_runtime.h>
#include <hip/hip_bf16.h>

#define DEVINL __device__ __forceinline__
typedef __hip_bfloat16 bf16;

static constexpr int N_NODES  = 50000;
static constexpr int N_EDGES  = 800000;
static constexpr int E_TOT    = 850000;   // + self loops
static constexpr int N_GRAPHS = 128;
static constexpr float NEG_SLOPE = 0.2f;

// Dual-path input load: isbf=1 -> storage is bf16, else fp32.
DEVINL float ldIn(const void* __restrict__ p, size_t i, int isbf) {
    if (isbf) return __bfloat162float(((const bf16*)p)[i]);
    return ((const float*)p)[i];
}

// ---------- runtime dtype detection ----------
// If x is stored fp32, the low 16 bits of each float (even ushorts, little-
// endian) are random mantissa bits -> interpreted as bf16 they are huge/NaN
// with overwhelming probability over 1024 samples. If stored bf16, every
// element is a plausible N(0,1) value (|v| <= ~6).
__global__ void detect_dtype_kernel(const unsigned short* __restrict__ xu,
                                    int* __restrict__ flag)
{
    int t = threadIdx.x;
    int bad = 0;
    for (int i = t; i < 1024; i += 64) {
        unsigned u = xu[2 * i];
        float v = __uint_as_float(u << 16);
        if (!(fabsf(v) <= 1e4f)) bad = 1;   // catches huge + NaN
    }
    unsigned long long m = __ballot(bad);
    if (t == 0) *flag = m ? 0 : 1;          // 1 = bf16 storage
}

// ---------- tiny setup: M[d][h] = sum_c We[d, h*64+c] * a_e[h, c] ----------
__global__ void build_M_kernel(const void* __restrict__ We1, const void* __restrict__ ae1,
                               const void* __restrict__ We2, const void* __restrict__ ae2,
                               const int* __restrict__ flagp,
                               float* __restrict__ M1, float* __restrict__ M2)
{
    const int isbf = *flagp;
    int t = threadIdx.x;
    if (t < 64) {
        int d = t >> 2, h = t & 3;
        float s = 0.f;
        for (int c = 0; c < 64; ++c)
            s += ldIn(We1, d * 256 + h * 64 + c, isbf) * ldIn(ae1, h * 64 + c, isbf);
        M1[d * 4 + h] = s;
    }
    if (t < 32) {
        int d = t >> 1, h = t & 1;
        float s = 0.f;
        for (int c = 0; c < 64; ++c)
            s += ldIn(We2, d * 128 + h * 64 + c, isbf) * ldIn(ae2, h * 64 + c, isbf);
        M2[d * 2 + h] = s;
    }
}

// ---------- self loops: per-dst mean of edge_attr ----------
__global__ void selfloop_acc_kernel(const int* __restrict__ dst, const void* __restrict__ eattr,
                                    const int* __restrict__ flagp,
                                    float* __restrict__ lsum, int* __restrict__ cnt)
{
    const int isbf = *flagp;
    int i = blockIdx.x * blockDim.x + threadIdx.x;   // i = e*16 + k
    if (i >= N_EDGES * 16) return;
    int e = i >> 4, k = i & 15;
    int d = dst[e];
    unsafeAtomicAdd(&lsum[d * 16 + k], ldIn(eattr, (size_t)i, isbf));
    if (k == 0) atomicAdd(&cnt[d], 1);
}

__global__ void selfloop_fin_kernel(float* __restrict__ lattr, const int* __restrict__ cnt)
{
    int i = blockIdx.x * blockDim.x + threadIdx.x;
    if (i >= N_NODES * 16) return;
    int n = i >> 4;
    lattr[i] = lattr[i] / fmaxf((float)cnt[n], 1.f);
}

// ---------- GEMM: C[N,M] = A[N,K] @ W[K,M], K tiled by 128, C stored bf16 ----------
template<int K, int M, bool A_INPUT>
__global__ __launch_bounds__(256)
void gemm_nn_kernel(const void* __restrict__ A, const void* __restrict__ W,
                    bf16* __restrict__ C, const int* __restrict__ flagp, int N)
{
    constexpr int BK = 128;
    __shared__ __align__(16) float Wt[BK * 64];
    __shared__ __align__(16) float At[32 * (BK + 1)];
    const int isbf = *flagp;
    const int tid = threadIdx.x;
    const int n0 = blockIdx.x * 32;
    const int m0 = blockIdx.y * 64;
    const int r  = tid & 31;
    const int mb = (tid >> 5) * 8;
    float acc[8] = {};
    for (int kb = 0; kb < K; kb += BK) {
        for (int i = tid; i < BK * 64; i += 256) {
            int k = i >> 6, m = i & 63;
            Wt[i] = ldIn(W, (size_t)(kb + k) * M + m0 + m, isbf);
        }
        for (int i = tid; i < 32 * BK; i += 256) {
            int rr = i >> 7, k = i & 127;          // BK = 128
            int n = n0 + rr;
            float v = 0.f;
            if (n < N) {
                size_t idx = (size_t)n * K + kb + k;
                v = A_INPUT ? ldIn(A, idx, isbf) : ((const float*)A)[idx];
            }
            At[rr * (BK + 1) + k] = v;
        }
        __syncthreads();
        for (int k = 0; k < BK; ++k) {
            float a = At[r * (BK + 1) + k];
            const float4* w4 = reinterpret_cast<const float4*>(&Wt[k * 64 + mb]);
            float4 w0 = w4[0], w1 = w4[1];
            acc[0] += a * w0.x; acc[1] += a * w0.y; acc[2] += a * w0.z; acc[3] += a * w0.w;
            acc[4] += a * w1.x; acc[5] += a * w1.y; acc[6] += a * w1.z; acc[7] += a * w1.w;
        }
        __syncthreads();
    }
    int n = n0 + r;
    if (n < N) {
        bf16* cp = &C[(size_t)n * M + m0 + mb];
        #pragma unroll
        for (int j = 0; j < 8; ++j) cp[j] = __float2bfloat16(acc[j]);
    }
}

// ---------- per-node attention logits: one wave per node ----------
template<int H>
__global__ __launch_bounds__(256)
void node_scores_kernel(const bf16* __restrict__ xs, const void* __restrict__ a_src,
                        const void* __restrict__ a_dst, const int* __restrict__ flagp,
                        float* __restrict__ sA, float* __restrict__ sD)
{
    const int isbf = *flagp;
    int wave = (blockIdx.x * 256 + threadIdx.x) >> 6;
    int lane = threadIdx.x & 63;
    if (wave >= N_NODES) return;
    #pragma unroll
    for (int h = 0; h < H; ++h) {
        float v  = __bfloat162float(xs[(size_t)wave * (H * 64) + h * 64 + lane]);
        float ps = v * ldIn(a_src, h * 64 + lane, isbf);
        float pd = v * ldIn(a_dst, h * 64 + lane, isbf);
        for (int off = 32; off; off >>= 1) {
            ps += __shfl_down(ps, off);
            pd += __shfl_down(pd, off);
        }
        if (lane == 0) { sA[wave * H + h] = ps; sD[wave * H + h] = pd; }
    }
}

// ---------- edge pass: score -> exp -> denom ----------
template<int H>
__global__ void edge_pass_kernel(const int* __restrict__ srcI, const int* __restrict__ dstI,
                                 const void* __restrict__ eattr, const float* __restrict__ lattr,
                                 const float* __restrict__ M, const int* __restrict__ flagp,
                                 const float* __restrict__ sA, const float* __restrict__ sD,
                                 bf16* __restrict__ exb, float* __restrict__ denom)
{
    const int isbf = *flagp;
    int e = blockIdx.x * blockDim.x + threadIdx.x;
    if (e >= E_TOT) return;
    int s, d;
    float attr[16];
    if (e < N_EDGES) {
        s = srcI[e]; d = dstI[e];
        #pragma unroll
        for (int k = 0; k < 16; ++k) attr[k] = ldIn(eattr, (size_t)e * 16 + k, isbf);
    } else {
        s = d = e - N_EDGES;
        #pragma unroll
        for (int k = 0; k < 16; ++k) attr[k] = lattr[(size_t)(e - N_EDGES) * 16 + k];
    }
    #pragma unroll
    for (int h = 0; h < H; ++h) {
        float se = 0.f;
        #pragma unroll
        for (int k = 0; k < 16; ++k) se += attr[k] * M[k * H + h];
        float sc = sA[s * H + h] + sD[d * H + h] + se;
        sc = sc > 0.f ? sc : NEG_SLOPE * sc;
        float ex = expf(sc);               // |sc| <~ 15 -> no overflow; max-sub not needed
        exb[e * H + h] = __float2bfloat16(ex);
        unsafeAtomicAdd(&denom[d * H + h], ex);
    }
}

// ---------- aggregation: one wave per edge, lane = channel ----------
template<int H>
__global__ __launch_bounds__(256)
void edge_agg_kernel(const int* __restrict__ srcI, const int* __restrict__ dstI,
                     const bf16* __restrict__ xs, const bf16* __restrict__ exb,
                     const float* __restrict__ denom, float* __restrict__ out)
{
    long long gid = (long long)blockIdx.x * blockDim.x + threadIdx.x;
    int e = (int)(gid >> 6);
    int lane = (int)(gid & 63);
    if (e >= E_TOT) return;
    int s, d;
    if (e < N_EDGES) { s = srcI[e]; d = dstI[e]; }
    else             { s = d = e - N_EDGES; }
    float w[H];
    #pragma unroll
    for (int h = 0; h < H; ++h) w[h] = 0.f;
    if (lane == 0) {
        #pragma unroll
        for (int h = 0; h < H; ++h)
            w[h] = __bfloat162float(exb[(size_t)e * H + h]) / (denom[d * H + h] + 1e-16f);
    }
    #pragma unroll
    for (int h = 0; h < H; ++h) w[h] = __shfl(w[h], 0);
    #pragma unroll
    for (int h = 0; h < H; ++h) {
        float v = __bfloat162float(xs[(size_t)s * (H * 64) + h * 64 + lane]);
        unsafeAtomicAdd(&out[(size_t)d * (H * 64) + h * 64 + lane], v * w[h]);
    }
}

// ---------- elementwise ----------
__global__ void bias_relu_kernel(float* __restrict__ h, const void* __restrict__ b,
                                 const int* __restrict__ flagp)
{
    const int isbf = *flagp;
    int i = blockIdx.x * blockDim.x + threadIdx.x;
    if (i >= N_NODES * 256) return;
    float v = h[i] + ldIn(b, i & 255, isbf);
    h[i] = v > 0.f ? v : 0.f;
}

__global__ void head_mean_kernel(const float* __restrict__ agg2, const void* __restrict__ b2,
                                 const int* __restrict__ flagp, float* __restrict__ h2)
{
    const int isbf = *flagp;
    int i = blockIdx.x * blockDim.x + threadIdx.x;
    if (i >= N_NODES * 64) return;
    int n = i >> 6, c = i & 63;
    h2[i] = 0.5f * (agg2[(size_t)n * 128 + c] + agg2[(size_t)n * 128 + 64 + c])
            + ldIn(b2, c, isbf);
}

// ---------- pooling: one block per graph, batch is sorted ----------
__global__ __launch_bounds__(256)
void pool_max_kernel(const float* __restrict__ h2, const int* __restrict__ batch,
                     float* __restrict__ g)
{
    int gi = blockIdx.x;
    int lo = 0, hi = N_NODES;
    while (lo < hi) { int mid = (lo + hi) >> 1; if (batch[mid] < gi) lo = mid + 1; else hi = mid; }
    int start = lo;
    lo = start; hi = N_NODES;
    while (lo < hi) { int mid = (lo + hi) >> 1; if (batch[mid] < gi + 1) lo = mid + 1; else hi = mid; }
    int end = lo;
    int c = threadIdx.x & 63, chunk = threadIdx.x >> 6;
    float m = -INFINITY;
    for (int n = start + chunk; n < end; n += 4) m = fmaxf(m, h2[(size_t)n * 64 + c]);
    __shared__ float sm[256];
    sm[threadIdx.x] = m;
    __syncthreads();
    if (threadIdx.x < 64) {
        m = fmaxf(fmaxf(sm[threadIdx.x], sm[threadIdx.x + 64]),
                  fmaxf(sm[threadIdx.x + 128], sm[threadIdx.x + 192]));
        g[gi * 64 + threadIdx.x] = m;
    }
}

// ---------- readout: g @ Wr + br ----------
__global__ void readout_kernel(const float* __restrict__ g, const void* __restrict__ Wr,
                               const void* __restrict__ br, const int* __restrict__ flagp,
                               void* __restrict__ out)
{
    const int isbf = *flagp;
    int gi = blockIdx.x;
    int lane = threadIdx.x;
    float p = g[gi * 64 + lane] * ldIn(Wr, lane, isbf);
    for (int off = 32; off; off >>= 1) p += __shfl_down(p, off);
    if (lane == 0) {
        float r = p + ldIn(br, 0, isbf);
        if (isbf) ((bf16*)out)[gi] = __float2bfloat16(r);
        else      ((float*)out)[gi] = r;
    }
}

extern "C" void kernel_launch(void* const* d_in, const int* in_sizes, int n_in,
                              void* d_out, int out_size, void* d_ws, size_t ws_size,
                              hipStream_t stream)
{
    const void* x     = d_in[0];
    const void* ea    = d_in[1];
    const int*  eidx  = (const int*)d_in[2];
    const int*  batch = (const int*)d_in[3];
    const void* W1  = d_in[4];
    const void* as1 = d_in[5];
    const void* ad1 = d_in[6];
    const void* We1 = d_in[7];
    const void* ae1 = d_in[8];
    const void* b1  = d_in[9];
    const void* W2  = d_in[10];
    const void* as2 = d_in[11];
    const void* ad2 = d_in[12];
    const void* We2 = d_in[13];
    const void* ae2 = d_in[14];
    const void* b2  = d_in[15];
    const void* Wr  = d_in[16];
    const void* br  = d_in[17];

    const int* srcI = eidx;
    const int* dstI = eidx + N_EDGES;

    // ---- workspace layout, peak ~90.7 MB ----
    float* ws    = (float*)d_ws;
    bf16*  xs    = (bf16*)ws;                 // layer1: N*256 bf16 = [0, 6.4M floats);
                                              // layer2 reuses as N*128 bf16
    float* agg1  = ws + 6400000;              // N*256 f32 -> [6.4M, 19.2M)
    float* agg2  = agg1;                      // N*128 f32, reuses agg1 (memset AFTER gemm2)
    bf16*  exb   = (bf16*)(ws + 19200000);    // E_TOT*4 bf16 = [19.2M, 20.9M)
    float* den1  = ws + 20900000;             // N*4
    float* den2  = ws + 21100000;             // N*2
    float* sA1   = ws + 21200000;             // N*4
    float* sD1   = ws + 21400000;             // N*4
    float* sA2   = ws + 21600000;             // N*2
    float* sD2   = ws + 21700000;             // N*2
    float* lattr = ws + 21800000;             // N*16
    int*   cnt   = (int*)(ws + 22600000);     // N
    int*   flag  = (int*)(ws + 22650000);     // 1
    float* M1    = ws + 22650016;             // 64
    float* M2    = M1 + 64;                   // 32
    float* gpool = M2 + 32;                   // 128*64
    float* h2b   = ws;                        // N*64 f32, reuses xs region (dead by then)

    hipMemsetAsync(cnt,  0, N_NODES * sizeof(int), stream);
    hipMemsetAsync(lattr,0, (size_t)N_NODES * 16 * sizeof(float), stream);
    hipMemsetAsync(den1, 0, (size_t)N_NODES * 4 * sizeof(float), stream);
    hipMemsetAsync(den2, 0, (size_t)N_NODES * 2 * sizeof(float), stream);
    hipMemsetAsync(agg1, 0, (size_t)N_NODES * 256 * sizeof(float), stream);

    detect_dtype_kernel<<<1, 64, 0, stream>>>((const unsigned short*)x, flag);
    build_M_kernel<<<1, 64, 0, stream>>>(We1, ae1, We2, ae2, flag, M1, M2);
    selfloop_acc_kernel<<<(N_EDGES * 16 + 255) / 256, 256, 0, stream>>>(dstI, ea, flag, lattr, cnt);
    selfloop_fin_kernel<<<(N_NODES * 16 + 255) / 256, 256, 0, stream>>>(lattr, cnt);

    // ----- layer 1 (H=4, concat) -----
    gemm_nn_kernel<128, 256, true><<<dim3((N_NODES + 31) / 32, 4), 256, 0, stream>>>(x, W1, xs, flag, N_NODES);
    node_scores_kernel<4><<<(N_NODES + 3) / 4, 256, 0, stream>>>(xs, as1, ad1, flag, sA1, sD1);
    edge_pass_kernel<4><<<(E_TOT + 255) / 256, 256, 0, stream>>>(srcI, dstI, ea, lattr, M1, flag, sA1, sD1, exb, den1);
    edge_agg_kernel<4><<<(int)(((long long)E_TOT * 64 + 255) / 256), 256, 0, stream>>>(srcI, dstI, xs, exb, den1, agg1);
    bias_relu_kernel<<<(N_NODES * 256 + 255) / 256, 256, 0, stream>>>(agg1, b1, flag);

    // ----- layer 2 (H=2, mean) -----
    gemm_nn_kernel<256, 128, false><<<dim3((N_NODES + 31) / 32, 2), 256, 0, stream>>>(agg1, W2, xs, flag, N_NODES);
    hipMemsetAsync(agg2, 0, (size_t)N_NODES * 128 * sizeof(float), stream);  // agg1 dead after gemm2
    node_scores_kernel<2><<<(N_NODES + 3) / 4, 256, 0, stream>>>(xs, as2, ad2, flag, sA2, sD2);
    edge_pass_kernel<2><<<(E_TOT + 255) / 256, 256, 0, stream>>>(srcI, dstI, ea, lattr, M2, flag, sA2, sD2, exb, den2);
    edge_agg_kernel<2><<<(int)(((long long)E_TOT * 64 + 255) / 256), 256, 0, stream>>>(srcI, dstI, xs, exb, den2, agg2);
    head_mean_kernel<<<(N_NODES * 64 + 255) / 256, 256, 0, stream>>>(agg2, b2, flag, h2b);

    // ----- pool + readout -----
    pool_max_kernel<<<N_GRAPHS, 256, 0, stream>>>(h2b, batch, gpool);
    readout_kernel<<<N_GRAPHS, 64, 0, stream>>>(gpool, Wr, br, flag, d_out);
}

// Round 3
// 1005.745 us; speedup vs baseline: 1.9510x; 1.9510x over previous
//
#include <hip/hip_runtime.h>
#include <hip/hip_bf16.h>

#define DEVINL __device__ __forceinline__
typedef __hip_bfloat16 bf16;

static constexpr int N_NODES  = 50000;
static constexpr int N_EDGES  = 800000;
static constexpr int N_GRAPHS = 128;
static constexpr float NEG_SLOPE = 0.2f;

// Dual-path input load: isbf=1 -> storage is bf16, else fp32.
DEVINL float ldIn(const void* __restrict__ p, size_t i, int isbf) {
    if (isbf) return __bfloat162float(((const bf16*)p)[i]);
    return ((const float*)p)[i];
}

// ---------- runtime dtype detection (see round-1 notes) ----------
__global__ void detect_dtype_kernel(const unsigned short* __restrict__ xu,
                                    int* __restrict__ flag)
{
    int t = threadIdx.x;
    int bad = 0;
    for (int i = t; i < 1024; i += 64) {
        unsigned u = xu[2 * i];
        float v = __uint_as_float(u << 16);
        if (!(fabsf(v) <= 1e4f)) bad = 1;
    }
    unsigned long long m = __ballot(bad);
    if (t == 0) *flag = m ? 0 : 1;          // 1 = bf16 storage
}

// ---------- tiny setup: M[d][h] = sum_c We[d, h*64+c] * a_e[h, c] ----------
__global__ void build_M_kernel(const void* __restrict__ We1, const void* __restrict__ ae1,
                               const void* __restrict__ We2, const void* __restrict__ ae2,
                               const int* __restrict__ flagp,
                               float* __restrict__ M1, float* __restrict__ M2)
{
    const int isbf = *flagp;
    int t = threadIdx.x;
    if (t < 64) {
        int d = t >> 2, h = t & 3;
        float s = 0.f;
        for (int c = 0; c < 64; ++c)
            s += ldIn(We1, d * 256 + h * 64 + c, isbf) * ldIn(ae1, h * 64 + c, isbf);
        M1[d * 4 + h] = s;
    }
    if (t < 32) {
        int d = t >> 1, h = t & 1;
        float s = 0.f;
        for (int c = 0; c < 64; ++c)
            s += ldIn(We2, d * 128 + h * 64 + c, isbf) * ldIn(ae2, h * 64 + c, isbf);
        M2[d * 2 + h] = s;
    }
}

// ---------- CSR build ----------
__global__ void csr_count_kernel(const int* __restrict__ dst, int* __restrict__ cnt)
{
    int e = blockIdx.x * blockDim.x + threadIdx.x;
    if (e >= N_EDGES) return;
    atomicAdd(&cnt[dst[e]], 1);
}

// single-block exclusive scan of cnt[0..N) -> row[0..N], cursor copy
__global__ __launch_bounds__(1024)
void csr_scan_kernel(const int* __restrict__ cnt, int* __restrict__ row,
                     int* __restrict__ cursor)
{
    __shared__ int buf[1024];
    __shared__ int carry;
    int tid = threadIdx.x;
    if (tid == 0) carry = 0;
    __syncthreads();
    for (int base = 0; base < N_NODES; base += 1024) {
        int v = (base + tid < N_NODES) ? cnt[base + tid] : 0;
        buf[tid] = v;
        __syncthreads();
        for (int off = 1; off < 1024; off <<= 1) {
            int t = (tid >= off) ? buf[tid - off] : 0;
            __syncthreads();
            buf[tid] += t;
            __syncthreads();
        }
        int excl = buf[tid] - v + carry;
        if (base + tid < N_NODES) { row[base + tid] = excl; cursor[base + tid] = excl; }
        __syncthreads();
        if (tid == 0) carry += buf[1023];
        __syncthreads();
    }
    if (threadIdx.x == 0) row[N_NODES] = carry;
}

__global__ void csr_scatter_kernel(const int* __restrict__ srcI, const int* __restrict__ dstI,
                                   int* __restrict__ cursor, int* __restrict__ srcS,
                                   int* __restrict__ dS, int* __restrict__ origE)
{
    int e = blockIdx.x * blockDim.x + threadIdx.x;
    if (e >= N_EDGES) return;
    int d = dstI[e];
    int pos = atomicAdd(&cursor[d], 1);
    srcS[pos] = srcI[e];
    dS[pos] = d;
    origE[pos] = e;
}

// ---------- self-loop attr: per-dst mean via CSR gather (no atomics) ----------
__global__ __launch_bounds__(256)
void selfloop_mean_kernel(const int* __restrict__ row, const int* __restrict__ origE,
                          const void* __restrict__ eattr, const int* __restrict__ flagp,
                          float* __restrict__ lattr)
{
    const int isbf = *flagp;
    int d = (blockIdx.x * 256 + threadIdx.x) >> 6;
    int lane = threadIdx.x & 63;
    if (d >= N_NODES) return;
    int b = row[d], eend = row[d + 1];
    int cntv = eend - b;
    int k = lane & 15, g = lane >> 4;
    float s = 0.f;
    for (int j = b + g; j < eend; j += 4) {
        int e = origE[j];
        s += ldIn(eattr, (size_t)e * 16 + k, isbf);
    }
    s += __shfl_down(s, 32);
    s += __shfl_down(s, 16);
    if (lane < 16) lattr[(size_t)d * 16 + k] = s / fmaxf((float)cntv, 1.f);
}

// ---------- GEMM: C[N,M] = A[N,K] @ W[K,M], K tiled by 128, C stored bf16 ----------
// AMODE: 0 = external input (isbf-dependent), 1 = bf16 workspace
template<int K, int M, int AMODE>
__global__ __launch_bounds__(256)
void gemm_nn_kernel(const void* __restrict__ A, const void* __restrict__ W,
                    bf16* __restrict__ C, const int* __restrict__ flagp, int N)
{
    constexpr int BK = 128;
    __shared__ __align__(16) float Wt[BK * 64];
    __shared__ __align__(16) float At[32 * (BK + 1)];
    const int isbf = *flagp;
    const int tid = threadIdx.x;
    const int n0 = blockIdx.x * 32;
    const int m0 = blockIdx.y * 64;
    const int r  = tid & 31;
    const int mb = (tid >> 5) * 8;
    float acc[8] = {};
    for (int kb = 0; kb < K; kb += BK) {
        for (int i = tid; i < BK * 64; i += 256) {
            int k = i >> 6, m = i & 63;
            Wt[i] = ldIn(W, (size_t)(kb + k) * M + m0 + m, isbf);
        }
        for (int i = tid; i < 32 * BK; i += 256) {
            int rr = i >> 7, k = i & 127;
            int n = n0 + rr;
            float v = 0.f;
            if (n < N) {
                size_t idx = (size_t)n * K + kb + k;
                v = (AMODE == 0) ? ldIn(A, idx, isbf)
                                 : __bfloat162float(((const bf16*)A)[idx]);
            }
            At[rr * (BK + 1) + k] = v;
        }
        __syncthreads();
        for (int k = 0; k < BK; ++k) {
            float a = At[r * (BK + 1) + k];
            const float4* w4 = reinterpret_cast<const float4*>(&Wt[k * 64 + mb]);
            float4 w0 = w4[0], w1 = w4[1];
            acc[0] += a * w0.x; acc[1] += a * w0.y; acc[2] += a * w0.z; acc[3] += a * w0.w;
            acc[4] += a * w1.x; acc[5] += a * w1.y; acc[6] += a * w1.z; acc[7] += a * w1.w;
        }
        __syncthreads();
    }
    int n = n0 + r;
    if (n < N) {
        bf16* cp = &C[(size_t)n * M + m0 + mb];
        #pragma unroll
        for (int j = 0; j < 8; ++j) cp[j] = __float2bfloat16(acc[j]);
    }
}

// ---------- per-node attention logits: one wave per node ----------
template<int H>
__global__ __launch_bounds__(256)
void node_scores_kernel(const bf16* __restrict__ xs, const void* __restrict__ a_src,
                        const void* __restrict__ a_dst, const int* __restrict__ flagp,
                        float* __restrict__ sA, float* __restrict__ sD)
{
    const int isbf = *flagp;
    int wave = (blockIdx.x * 256 + threadIdx.x) >> 6;
    int lane = threadIdx.x & 63;
    if (wave >= N_NODES) return;
    #pragma unroll
    for (int h = 0; h < H; ++h) {
        float v  = __bfloat162float(xs[(size_t)wave * (H * 64) + h * 64 + lane]);
        float ps = v * ldIn(a_src, h * 64 + lane, isbf);
        float pd = v * ldIn(a_dst, h * 64 + lane, isbf);
        for (int off = 32; off; off >>= 1) {
            ps += __shfl_down(ps, off);
            pd += __shfl_down(pd, off);
        }
        if (lane == 0) { sA[wave * H + h] = ps; sD[wave * H + h] = pd; }
    }
}

// ---------- edge pass over SORTED edges: exp(leaky_relu(score)), no atomics ----------
template<int H>
__global__ void edge_pass_kernel(const int* __restrict__ srcS, const int* __restrict__ dS,
                                 const int* __restrict__ origE,
                                 const void* __restrict__ eattr, const int* __restrict__ flagp,
                                 const float* __restrict__ M,
                                 const float* __restrict__ sA, const float* __restrict__ sD,
                                 float* __restrict__ exw)
{
    const int isbf = *flagp;
    int j = blockIdx.x * blockDim.x + threadIdx.x;
    if (j >= N_EDGES) return;
    int e = origE[j], s = srcS[j], d = dS[j];
    float attr[16];
    #pragma unroll
    for (int k = 0; k < 16; ++k) attr[k] = ldIn(eattr, (size_t)e * 16 + k, isbf);
    #pragma unroll
    for (int h = 0; h < H; ++h) {
        float se = 0.f;
        #pragma unroll
        for (int k = 0; k < 16; ++k) se += attr[k] * M[k * H + h];
        float sc = sA[s * H + h] + sD[d * H + h] + se;
        sc = sc > 0.f ? sc : NEG_SLOPE * sc;
        exw[(size_t)j * H + h] = expf(sc);   // |sc| <~ 15, safe in fp32
    }
}

// ---------- self-loop edge pass: one thread per node ----------
template<int H>
__global__ void self_pass_kernel(const float* __restrict__ lattr, const float* __restrict__ M,
                                 const float* __restrict__ sA, const float* __restrict__ sD,
                                 float* __restrict__ exSelf)
{
    int n = blockIdx.x * blockDim.x + threadIdx.x;
    if (n >= N_NODES) return;
    float attr[16];
    #pragma unroll
    for (int k = 0; k < 16; ++k) attr[k] = lattr[(size_t)n * 16 + k];
    #pragma unroll
    for (int h = 0; h < H; ++h) {
        float se = 0.f;
        #pragma unroll
        for (int k = 0; k < 16; ++k) se += attr[k] * M[k * H + h];
        float sc = sA[n * H + h] + sD[n * H + h] + se;
        sc = sc > 0.f ? sc : NEG_SLOPE * sc;
        exSelf[(size_t)n * H + h] = expf(sc);
    }
}

// ---------- fused aggregation: one wave per dst node, lane = channel ----------
// LAYER 1: out = relu(agg + b1) -> bf16 h1[N,256]
// LAYER 2: out = mean_heads(agg) + b2 -> fp32 h2[N,64]
template<int H, int LAYER>
__global__ __launch_bounds__(256)
void agg_fused_kernel(const int* __restrict__ row, const int* __restrict__ srcS,
                      const bf16* __restrict__ xs, const float* __restrict__ exw,
                      const float* __restrict__ exSelf, const void* __restrict__ bias,
                      const int* __restrict__ flagp, void* __restrict__ out)
{
    const int isbf = *flagp;
    int d = (blockIdx.x * 256 + threadIdx.x) >> 6;
    int lane = threadIdx.x & 63;
    if (d >= N_NODES) return;
    float acc[H], den[H];
    #pragma unroll
    for (int h = 0; h < H; ++h) {
        float w = exSelf[(size_t)d * H + h];
        den[h] = w;
        acc[h] = w * __bfloat162float(xs[(size_t)d * (H * 64) + h * 64 + lane]);
    }
    int b = row[d], eend = row[d + 1];
    for (int j = b; j < eend; ++j) {
        int s = srcS[j];
        const bf16* xp = &xs[(size_t)s * (H * 64) + lane];
        #pragma unroll
        for (int h = 0; h < H; ++h) {
            float w = exw[(size_t)j * H + h];
            den[h] += w;
            acc[h] += w * __bfloat162float(xp[h * 64]);
        }
    }
    if (LAYER == 1) {
        bf16* op = &((bf16*)out)[(size_t)d * (H * 64) + lane];
        #pragma unroll
        for (int h = 0; h < H; ++h) {
            float v = acc[h] / (den[h] + 1e-16f) + ldIn(bias, h * 64 + lane, isbf);
            op[h * 64] = __float2bfloat16(v > 0.f ? v : 0.f);
        }
    } else {
        float m = 0.f;
        #pragma unroll
        for (int h = 0; h < H; ++h) m += acc[h] / (den[h] + 1e-16f);
        ((float*)out)[(size_t)d * 64 + lane] = m / (float)H + ldIn(bias, lane, isbf);
    }
}

// ---------- pooling: one block per graph, batch is sorted ----------
__global__ __launch_bounds__(256)
void pool_max_kernel(const float* __restrict__ h2, const int* __restrict__ batch,
                     float* __restrict__ g)
{
    int gi = blockIdx.x;
    int lo = 0, hi = N_NODES;
    while (lo < hi) { int mid = (lo + hi) >> 1; if (batch[mid] < gi) lo = mid + 1; else hi = mid; }
    int start = lo;
    lo = start; hi = N_NODES;
    while (lo < hi) { int mid = (lo + hi) >> 1; if (batch[mid] < gi + 1) lo = mid + 1; else hi = mid; }
    int end = lo;
    int c = threadIdx.x & 63, chunk = threadIdx.x >> 6;
    float m = -INFINITY;
    for (int n = start + chunk; n < end; n += 4) m = fmaxf(m, h2[(size_t)n * 64 + c]);
    __shared__ float sm[256];
    sm[threadIdx.x] = m;
    __syncthreads();
    if (threadIdx.x < 64) {
        m = fmaxf(fmaxf(sm[threadIdx.x], sm[threadIdx.x + 64]),
                  fmaxf(sm[threadIdx.x + 128], sm[threadIdx.x + 192]));
        g[gi * 64 + threadIdx.x] = m;
    }
}

// ---------- readout: g @ Wr + br ----------
__global__ void readout_kernel(const float* __restrict__ g, const void* __restrict__ Wr,
                               const void* __restrict__ br, const int* __restrict__ flagp,
                               void* __restrict__ out)
{
    const int isbf = *flagp;
    int gi = blockIdx.x;
    int lane = threadIdx.x;
    float p = g[gi * 64 + lane] * ldIn(Wr, lane, isbf);
    for (int off = 32; off; off >>= 1) p += __shfl_down(p, off);
    if (lane == 0) {
        float r = p + ldIn(br, 0, isbf);
        if (isbf) ((bf16*)out)[gi] = __float2bfloat16(r);
        else      ((float*)out)[gi] = r;
    }
}

extern "C" void kernel_launch(void* const* d_in, const int* in_sizes, int n_in,
                              void* d_out, int out_size, void* d_ws, size_t ws_size,
                              hipStream_t stream)
{
    const void* x     = d_in[0];
    const void* ea    = d_in[1];
    const int*  eidx  = (const int*)d_in[2];
    const int*  batch = (const int*)d_in[3];
    const void* W1  = d_in[4];
    const void* as1 = d_in[5];
    const void* ad1 = d_in[6];
    const void* We1 = d_in[7];
    const void* ae1 = d_in[8];
    const void* b1  = d_in[9];
    const void* W2  = d_in[10];
    const void* as2 = d_in[11];
    const void* ad2 = d_in[12];
    const void* We2 = d_in[13];
    const void* ae2 = d_in[14];
    const void* b2  = d_in[15];
    const void* Wr  = d_in[16];
    const void* br  = d_in[17];

    const int* srcI = eidx;
    const int* dstI = eidx + N_EDGES;

    // ---- workspace layout (float-index offsets), peak ~81 MB ----
    float* ws    = (float*)d_ws;
    bf16*  xs    = (bf16*)ws;                     // [0, 6.4M): N*256 bf16 (L2: N*128 bf16)
    bf16*  h1    = (bf16*)(ws + 6400000);         // [6.4M, 12.8M): N*256 bf16
    float* h2    = ws + 6400000;                  // N*64 fp32, overlays h1 (dead after gemm2)
    float* exw   = ws + 12800000;                 // [12.8M, 16M): E*4 fp32 (L2 uses E*2)
    float* exS   = ws + 16000000;                 // N*4
    float* sA1   = ws + 16200000;                 // N*4
    float* sD1   = ws + 16400000;                 // N*4
    float* sA2   = ws + 16600000;                 // N*2
    float* sD2   = ws + 16700000;                 // N*2
    float* lattr = ws + 16800000;                 // N*16
    int*   ib    = (int*)(ws + 17600000);         // int region
    int*   row    = ib;                           // N+1
    int*   cursor = ib + 50016;                   // N
    int*   cnt    = ib + 100032;                  // N
    int*   srcS   = ib + 150048;                  // E
    int*   dS     = ib + 950048;                  // E
    int*   origE  = ib + 1750048;                 // E
    float* misc  = ws + 17600000 + 2550048;
    int*   flag  = (int*)misc;                    // 1
    float* M1    = misc + 16;                     // 64
    float* M2    = misc + 80;                     // 32
    float* gpool = misc + 112;                    // 128*64

    hipMemsetAsync(cnt, 0, N_NODES * sizeof(int), stream);

    detect_dtype_kernel<<<1, 64, 0, stream>>>((const unsigned short*)x, flag);
    build_M_kernel<<<1, 64, 0, stream>>>(We1, ae1, We2, ae2, flag, M1, M2);

    // ----- CSR over dst -----
    csr_count_kernel<<<(N_EDGES + 255) / 256, 256, 0, stream>>>(dstI, cnt);
    csr_scan_kernel<<<1, 1024, 0, stream>>>(cnt, row, cursor);
    csr_scatter_kernel<<<(N_EDGES + 255) / 256, 256, 0, stream>>>(srcI, dstI, cursor, srcS, dS, origE);
    selfloop_mean_kernel<<<(N_NODES + 3) / 4, 256, 0, stream>>>(row, origE, ea, flag, lattr);

    // ----- layer 1 (H=4, concat) -----
    gemm_nn_kernel<128, 256, 0><<<dim3((N_NODES + 31) / 32, 4), 256, 0, stream>>>(x, W1, xs, flag, N_NODES);
    node_scores_kernel<4><<<(N_NODES + 3) / 4, 256, 0, stream>>>(xs, as1, ad1, flag, sA1, sD1);
    edge_pass_kernel<4><<<(N_EDGES + 255) / 256, 256, 0, stream>>>(srcS, dS, origE, ea, flag, M1, sA1, sD1, exw);
    self_pass_kernel<4><<<(N_NODES + 255) / 256, 256, 0, stream>>>(lattr, M1, sA1, sD1, exS);
    agg_fused_kernel<4, 1><<<(N_NODES + 3) / 4, 256, 0, stream>>>(row, srcS, xs, exw, exS, b1, flag, h1);

    // ----- layer 2 (H=2, mean) -----
    gemm_nn_kernel<256, 128, 1><<<dim3((N_NODES + 31) / 32, 2), 256, 0, stream>>>(h1, W2, xs, flag, N_NODES);
    node_scores_kernel<2><<<(N_NODES + 3) / 4, 256, 0, stream>>>(xs, as2, ad2, flag, sA2, sD2);
    edge_pass_kernel<2><<<(N_EDGES + 255) / 256, 256, 0, stream>>>(srcS, dS, origE, ea, flag, M2, sA2, sD2, exw);
    self_pass_kernel<2><<<(N_NODES + 255) / 256, 256, 0, stream>>>(lattr, M2, sA2, sD2, exS);
    agg_fused_kernel<2, 2><<<(N_NODES + 3) / 4, 256, 0, stream>>>(row, srcS, xs, exw, exS, b2, flag, h2);

    // ----- pool + readout -----
    pool_max_kernel<<<N_GRAPHS, 256, 0, stream>>>(h2, batch, gpool);
    readout_kernel<<<N_GRAPHS, 64, 0, stream>>>(gpool, Wr, br, flag, d_out);
}

// Round 4
// 763.585 us; speedup vs baseline: 2.5698x; 1.3171x over previous
//
#include <hip/hip_runtime.h>
#include <hip/hip_bf16.h>

#define DEVINL __device__ __forceinline__
typedef __hip_bfloat16 bf16;

typedef __attribute__((ext_vector_type(8))) __bf16 bf16x8;
typedef __attribute__((ext_vector_type(4))) float f32x4;

static constexpr int N_NODES  = 50000;
static constexpr int N_EDGES  = 800000;
static constexpr int N_GRAPHS = 128;
static constexpr float NEG_SLOPE = 0.2f;

// Dual-path input load: isbf=1 -> storage is bf16, else fp32.
DEVINL float ldIn(const void* __restrict__ p, size_t i, int isbf) {
    if (isbf) return __bfloat162float(((const bf16*)p)[i]);
    return ((const float*)p)[i];
}

DEVINL unsigned short f2bf(float f) {
    bf16 b = __float2bfloat16(f);
    return *reinterpret_cast<unsigned short*>(&b);
}

// ---------- runtime dtype detection (see round-1 notes) ----------
__global__ void detect_dtype_kernel(const unsigned short* __restrict__ xu,
                                    int* __restrict__ flag)
{
    int t = threadIdx.x;
    int bad = 0;
    for (int i = t; i < 1024; i += 64) {
        unsigned u = xu[2 * i];
        float v = __uint_as_float(u << 16);
        if (!(fabsf(v) <= 1e4f)) bad = 1;
    }
    unsigned long long m = __ballot(bad);
    if (t == 0) *flag = m ? 0 : 1;          // 1 = bf16 storage
}

// ---------- tiny setup: M[d][h] = sum_c We[d, h*64+c] * a_e[h, c] ----------
__global__ void build_M_kernel(const void* __restrict__ We1, const void* __restrict__ ae1,
                               const void* __restrict__ We2, const void* __restrict__ ae2,
                               const int* __restrict__ flagp,
                               float* __restrict__ M1, float* __restrict__ M2)
{
    const int isbf = *flagp;
    int t = threadIdx.x;
    if (t < 64) {
        int d = t >> 2, h = t & 3;
        float s = 0.f;
        for (int c = 0; c < 64; ++c)
            s += ldIn(We1, d * 256 + h * 64 + c, isbf) * ldIn(ae1, h * 64 + c, isbf);
        M1[d * 4 + h] = s;
    }
    if (t < 32) {
        int d = t >> 1, h = t & 1;
        float s = 0.f;
        for (int c = 0; c < 64; ++c)
            s += ldIn(We2, d * 128 + h * 64 + c, isbf) * ldIn(ae2, h * 64 + c, isbf);
        M2[d * 2 + h] = s;
    }
}

// ---------- pack W[K,M] into MFMA B-fragment order: Wfrag[ct][ks][lane][j] ----------
// b_frag for lane: B[k = ks*32 + (lane>>4)*8 + j][n = ct*16 + (lane&15)]
template<int K, int M>
__global__ void build_wfrag_kernel(const void* __restrict__ W, const int* __restrict__ flagp,
                                   bf16* __restrict__ Wfrag)
{
    constexpr int KS = K / 32;
    const int isbf = *flagp;
    int idx = blockIdx.x * 256 + threadIdx.x;
    constexpr int total = (M / 16) * KS * 64 * 8;
    if (idx >= total) return;
    int j    = idx & 7;
    int lane = (idx >> 3) & 63;
    int rem  = idx >> 9;
    int ks   = rem % KS;
    int ct   = rem / KS;
    int k = ks * 32 + (lane >> 4) * 8 + j;
    int n = ct * 16 + (lane & 15);
    Wfrag[idx] = __float2bfloat16(ldIn(W, (size_t)k * M + n, isbf));
}

// ---------- MFMA GEMM: C[N,M] = A[N,K] @ W[K,M], C stored bf16 ----------
// AMODE 0: A is external input (fp32 or bf16 per flag); AMODE 1: A is bf16 ws.
template<int K, int M, int AMODE>
__global__ __launch_bounds__(256)
void gemm_mfma_kernel(const void* __restrict__ A, const bf16* __restrict__ Wfrag,
                      bf16* __restrict__ C, const int* __restrict__ flagp, int N)
{
    constexpr int KS = K / 32, CT = M / 16;
    constexpr int LDA = K + 8;                       // +16B pad: breaks bank aliasing
    __shared__ __align__(16) unsigned short Asm[64 * LDA];
    const int isbf = *flagp;
    const int tid  = threadIdx.x;
    const int wave = tid >> 6, lane = tid & 63;
    const int n0 = blockIdx.x * 64;

    // ---- stage A tile (64 rows x K) into LDS as bf16, 8 elems/thread/iter ----
    for (int i = tid; i < 64 * (K / 8); i += 256) {
        int r  = i / (K / 8);
        int kc = (i % (K / 8)) * 8;
        int n  = n0 + r;
        unsigned short v[8] = {0, 0, 0, 0, 0, 0, 0, 0};
        if (n < N) {
            size_t base = (size_t)n * K + kc;
            if (AMODE == 1 || isbf) {
                *reinterpret_cast<uint4*>(v) =
                    *reinterpret_cast<const uint4*>((const unsigned short*)A + base);
            } else {
                const float* Af = (const float*)A + base;
                float4 f0 = *reinterpret_cast<const float4*>(Af);
                float4 f1 = *reinterpret_cast<const float4*>(Af + 4);
                v[0] = f2bf(f0.x); v[1] = f2bf(f0.y); v[2] = f2bf(f0.z); v[3] = f2bf(f0.w);
                v[4] = f2bf(f1.x); v[5] = f2bf(f1.y); v[6] = f2bf(f1.z); v[7] = f2bf(f1.w);
            }
        }
        *reinterpret_cast<uint4*>(&Asm[r * LDA + kc]) = *reinterpret_cast<uint4*>(v);
    }
    __syncthreads();

    f32x4 acc[CT];
    #pragma unroll
    for (int ct = 0; ct < CT; ++ct) acc[ct] = (f32x4){0.f, 0.f, 0.f, 0.f};

    const int arow  = wave * 16 + (lane & 15);
    const int akoff = (lane >> 4) * 8;
    #pragma unroll
    for (int ks = 0; ks < KS; ++ks) {
        bf16x8 af = *reinterpret_cast<const bf16x8*>(&Asm[arow * LDA + ks * 32 + akoff]);
        #pragma unroll
        for (int ct = 0; ct < CT; ++ct) {
            bf16x8 bfr = *reinterpret_cast<const bf16x8*>(
                &Wfrag[(((size_t)ct * KS + ks) * 64 + lane) * 8]);
            acc[ct] = __builtin_amdgcn_mfma_f32_16x16x32_bf16(af, bfr, acc[ct], 0, 0, 0);
        }
    }

    // ---- store: row = (lane>>4)*4 + reg, col = lane&15 (verified C/D layout) ----
    const int crow0 = n0 + wave * 16 + (lane >> 4) * 4;
    const int ccol  = lane & 15;
    #pragma unroll
    for (int ct = 0; ct < CT; ++ct) {
        #pragma unroll
        for (int r = 0; r < 4; ++r) {
            int row = crow0 + r;
            if (row < N) C[(size_t)row * M + ct * 16 + ccol] = __float2bfloat16(acc[ct][r]);
        }
    }
}

// ---------- CSR build ----------
__global__ void csr_count_kernel(const int* __restrict__ dst, int* __restrict__ cnt)
{
    int e = blockIdx.x * blockDim.x + threadIdx.x;
    if (e >= N_EDGES) return;
    atomicAdd(&cnt[dst[e]], 1);
}

__global__ __launch_bounds__(1024)
void csr_scan_kernel(const int* __restrict__ cnt, int* __restrict__ row,
                     int* __restrict__ cursor)
{
    __shared__ int buf[1024];
    __shared__ int carry;
    int tid = threadIdx.x;
    if (tid == 0) carry = 0;
    __syncthreads();
    for (int base = 0; base < N_NODES; base += 1024) {
        int v = (base + tid < N_NODES) ? cnt[base + tid] : 0;
        buf[tid] = v;
        __syncthreads();
        for (int off = 1; off < 1024; off <<= 1) {
            int t = (tid >= off) ? buf[tid - off] : 0;
            __syncthreads();
            buf[tid] += t;
            __syncthreads();
        }
        int excl = buf[tid] - v + carry;
        if (base + tid < N_NODES) { row[base + tid] = excl; cursor[base + tid] = excl; }
        __syncthreads();
        if (tid == 0) carry += buf[1023];
        __syncthreads();
    }
    if (threadIdx.x == 0) row[N_NODES] = carry;
}

__global__ void csr_scatter_kernel(const int* __restrict__ srcI, const int* __restrict__ dstI,
                                   int* __restrict__ cursor, int* __restrict__ srcS,
                                   int* __restrict__ dS, int* __restrict__ origE)
{
    int e = blockIdx.x * blockDim.x + threadIdx.x;
    if (e >= N_EDGES) return;
    int d = dstI[e];
    int pos = atomicAdd(&cursor[d], 1);
    srcS[pos] = srcI[e];
    dS[pos] = d;
    origE[pos] = e;
}

// ---------- self-loop attr: per-dst mean via CSR gather ----------
__global__ __launch_bounds__(256)
void selfloop_mean_kernel(const int* __restrict__ row, const int* __restrict__ origE,
                          const void* __restrict__ eattr, const int* __restrict__ flagp,
                          float* __restrict__ lattr)
{
    const int isbf = *flagp;
    int d = (blockIdx.x * 256 + threadIdx.x) >> 6;
    int lane = threadIdx.x & 63;
    if (d >= N_NODES) return;
    int b = row[d], eend = row[d + 1];
    int cntv = eend - b;
    int k = lane & 15, g = lane >> 4;
    float s = 0.f;
    for (int j = b + g; j < eend; j += 4) {
        int e = origE[j];
        s += ldIn(eattr, (size_t)e * 16 + k, isbf);
    }
    s += __shfl_down(s, 32);
    s += __shfl_down(s, 16);
    if (lane < 16) lattr[(size_t)d * 16 + k] = s / fmaxf((float)cntv, 1.f);
}

// ---------- per-node attention logits: one wave per node ----------
template<int H>
__global__ __launch_bounds__(256)
void node_scores_kernel(const bf16* __restrict__ xs, const void* __restrict__ a_src,
                        const void* __restrict__ a_dst, const int* __restrict__ flagp,
                        float* __restrict__ sA, float* __restrict__ sD)
{
    const int isbf = *flagp;
    int wave = (blockIdx.x * 256 + threadIdx.x) >> 6;
    int lane = threadIdx.x & 63;
    if (wave >= N_NODES) return;
    #pragma unroll
    for (int h = 0; h < H; ++h) {
        float v  = __bfloat162float(xs[(size_t)wave * (H * 64) + h * 64 + lane]);
        float ps = v * ldIn(a_src, h * 64 + lane, isbf);
        float pd = v * ldIn(a_dst, h * 64 + lane, isbf);
        for (int off = 32; off; off >>= 1) {
            ps += __shfl_down(ps, off);
            pd += __shfl_down(pd, off);
        }
        if (lane == 0) { sA[wave * H + h] = ps; sD[wave * H + h] = pd; }
    }
}

// ---------- edge pass over SORTED edges ----------
template<int H>
__global__ void edge_pass_kernel(const int* __restrict__ srcS, const int* __restrict__ dS,
                                 const int* __restrict__ origE,
                                 const void* __restrict__ eattr, const int* __restrict__ flagp,
                                 const float* __restrict__ M,
                                 const float* __restrict__ sA, const float* __restrict__ sD,
                                 float* __restrict__ exw)
{
    const int isbf = *flagp;
    int j = blockIdx.x * blockDim.x + threadIdx.x;
    if (j >= N_EDGES) return;
    int e = origE[j], s = srcS[j], d = dS[j];
    float attr[16];
    #pragma unroll
    for (int k = 0; k < 16; ++k) attr[k] = ldIn(eattr, (size_t)e * 16 + k, isbf);
    #pragma unroll
    for (int h = 0; h < H; ++h) {
        float se = 0.f;
        #pragma unroll
        for (int k = 0; k < 16; ++k) se += attr[k] * M[k * H + h];
        float sc = sA[s * H + h] + sD[d * H + h] + se;
        sc = sc > 0.f ? sc : NEG_SLOPE * sc;
        exw[(size_t)j * H + h] = expf(sc);   // |sc| <~ 15, safe in fp32
    }
}

// ---------- self-loop edge pass ----------
template<int H>
__global__ void self_pass_kernel(const float* __restrict__ lattr, const float* __restrict__ M,
                                 const float* __restrict__ sA, const float* __restrict__ sD,
                                 float* __restrict__ exSelf)
{
    int n = blockIdx.x * blockDim.x + threadIdx.x;
    if (n >= N_NODES) return;
    float attr[16];
    #pragma unroll
    for (int k = 0; k < 16; ++k) attr[k] = lattr[(size_t)n * 16 + k];
    #pragma unroll
    for (int h = 0; h < H; ++h) {
        float se = 0.f;
        #pragma unroll
        for (int k = 0; k < 16; ++k) se += attr[k] * M[k * H + h];
        float sc = sA[n * H + h] + sD[n * H + h] + se;
        sc = sc > 0.f ? sc : NEG_SLOPE * sc;
        exSelf[(size_t)n * H + h] = expf(sc);
    }
}

// ---------- fused aggregation: one wave per dst node, lane = channel ----------
template<int H, int LAYER>
__global__ __launch_bounds__(256)
void agg_fused_kernel(const int* __restrict__ row, const int* __restrict__ srcS,
                      const bf16* __restrict__ xs, const float* __restrict__ exw,
                      const float* __restrict__ exSelf, const void* __restrict__ bias,
                      const int* __restrict__ flagp, void* __restrict__ out)
{
    const int isbf = *flagp;
    int d = (blockIdx.x * 256 + threadIdx.x) >> 6;
    int lane = threadIdx.x & 63;
    if (d >= N_NODES) return;
    float acc[H], den[H];
    #pragma unroll
    for (int h = 0; h < H; ++h) {
        float w = exSelf[(size_t)d * H + h];
        den[h] = w;
        acc[h] = w * __bfloat162float(xs[(size_t)d * (H * 64) + h * 64 + lane]);
    }
    int b = row[d], eend = row[d + 1];
    for (int j = b; j < eend; ++j) {
        int s = srcS[j];
        const bf16* xp = &xs[(size_t)s * (H * 64) + lane];
        #pragma unroll
        for (int h = 0; h < H; ++h) {
            float w = exw[(size_t)j * H + h];
            den[h] += w;
            acc[h] += w * __bfloat162float(xp[h * 64]);
        }
    }
    if (LAYER == 1) {
        bf16* op = &((bf16*)out)[(size_t)d * (H * 64) + lane];
        #pragma unroll
        for (int h = 0; h < H; ++h) {
            float v = acc[h] / (den[h] + 1e-16f) + ldIn(bias, h * 64 + lane, isbf);
            op[h * 64] = __float2bfloat16(v > 0.f ? v : 0.f);
        }
    } else {
        float m = 0.f;
        #pragma unroll
        for (int h = 0; h < H; ++h) m += acc[h] / (den[h] + 1e-16f);
        ((float*)out)[(size_t)d * 64 + lane] = m / (float)H + ldIn(bias, lane, isbf);
    }
}

// ---------- pooling ----------
__global__ __launch_bounds__(256)
void pool_max_kernel(const float* __restrict__ h2, const int* __restrict__ batch,
                     float* __restrict__ g)
{
    int gi = blockIdx.x;
    int lo = 0, hi = N_NODES;
    while (lo < hi) { int mid = (lo + hi) >> 1; if (batch[mid] < gi) lo = mid + 1; else hi = mid; }
    int start = lo;
    lo = start; hi = N_NODES;
    while (lo < hi) { int mid = (lo + hi) >> 1; if (batch[mid] < gi + 1) lo = mid + 1; else hi = mid; }
    int end = lo;
    int c = threadIdx.x & 63, chunk = threadIdx.x >> 6;
    float m = -INFINITY;
    for (int n = start + chunk; n < end; n += 4) m = fmaxf(m, h2[(size_t)n * 64 + c]);
    __shared__ float sm[256];
    sm[threadIdx.x] = m;
    __syncthreads();
    if (threadIdx.x < 64) {
        m = fmaxf(fmaxf(sm[threadIdx.x], sm[threadIdx.x + 64]),
                  fmaxf(sm[threadIdx.x + 128], sm[threadIdx.x + 192]));
        g[gi * 64 + threadIdx.x] = m;
    }
}

// ---------- readout ----------
__global__ void readout_kernel(const float* __restrict__ g, const void* __restrict__ Wr,
                               const void* __restrict__ br, const int* __restrict__ flagp,
                               void* __restrict__ out)
{
    const int isbf = *flagp;
    int gi = blockIdx.x;
    int lane = threadIdx.x;
    float p = g[gi * 64 + lane] * ldIn(Wr, lane, isbf);
    for (int off = 32; off; off >>= 1) p += __shfl_down(p, off);
    if (lane == 0) {
        float r = p + ldIn(br, 0, isbf);
        if (isbf) ((bf16*)out)[gi] = __float2bfloat16(r);
        else      ((float*)out)[gi] = r;
    }
}

extern "C" void kernel_launch(void* const* d_in, const int* in_sizes, int n_in,
                              void* d_out, int out_size, void* d_ws, size_t ws_size,
                              hipStream_t stream)
{
    const void* x     = d_in[0];
    const void* ea    = d_in[1];
    const int*  eidx  = (const int*)d_in[2];
    const int*  batch = (const int*)d_in[3];
    const void* W1  = d_in[4];
    const void* as1 = d_in[5];
    const void* ad1 = d_in[6];
    const void* We1 = d_in[7];
    const void* ae1 = d_in[8];
    const void* b1  = d_in[9];
    const void* W2  = d_in[10];
    const void* as2 = d_in[11];
    const void* ad2 = d_in[12];
    const void* We2 = d_in[13];
    const void* ae2 = d_in[14];
    const void* b2  = d_in[15];
    const void* Wr  = d_in[16];
    const void* br  = d_in[17];

    const int* srcI = eidx;
    const int* dstI = eidx + N_EDGES;

    // ---- workspace layout (float-index offsets), peak ~81 MB ----
    float* ws    = (float*)d_ws;
    bf16*  xs    = (bf16*)ws;                     // [0, 6.4M): N*256 bf16 (L2: N*128 bf16)
    bf16*  h1    = (bf16*)(ws + 6400000);         // [6.4M, 12.8M): N*256 bf16
    float* h2    = ws + 6400000;                  // N*64 fp32, overlays h1 (dead after gemm2)
    float* exw   = ws + 12800000;                 // E*4 fp32 (L2 uses E*2)
    float* exS   = ws + 16000000;                 // N*4
    float* sA1   = ws + 16200000;                 // N*4
    float* sD1   = ws + 16400000;                 // N*4
    float* sA2   = ws + 16600000;                 // N*2
    float* sD2   = ws + 16700000;                 // N*2
    float* lattr = ws + 16800000;                 // N*16
    int*   ib    = (int*)(ws + 17600000);         // int region
    int*   row    = ib;                           // N+1
    int*   cursor = ib + 50016;                   // N
    int*   cnt    = ib + 100032;                  // N
    int*   srcS   = ib + 150048;                  // E
    int*   dS     = ib + 950048;                  // E
    int*   origE  = ib + 1750048;                 // E
    float* misc  = ws + 17600000 + 2550048;
    int*   flag  = (int*)misc;                    // 1
    float* M1    = misc + 16;                     // 64
    float* M2    = misc + 80;                     // 32
    float* gpool = misc + 112;                    // 128*64
    bf16*  wf1   = (bf16*)(misc + 8320);          // 32768 bf16 (16384 floats)
    bf16*  wf2   = (bf16*)(misc + 8320 + 16384);  // 32768 bf16

    hipMemsetAsync(cnt, 0, N_NODES * sizeof(int), stream);

    detect_dtype_kernel<<<1, 64, 0, stream>>>((const unsigned short*)x, flag);
    build_M_kernel<<<1, 64, 0, stream>>>(We1, ae1, We2, ae2, flag, M1, M2);
    build_wfrag_kernel<128, 256><<<128, 256, 0, stream>>>(W1, flag, wf1);
    build_wfrag_kernel<256, 128><<<128, 256, 0, stream>>>(W2, flag, wf2);

    // ----- CSR over dst -----
    csr_count_kernel<<<(N_EDGES + 255) / 256, 256, 0, stream>>>(dstI, cnt);
    csr_scan_kernel<<<1, 1024, 0, stream>>>(cnt, row, cursor);
    csr_scatter_kernel<<<(N_EDGES + 255) / 256, 256, 0, stream>>>(srcI, dstI, cursor, srcS, dS, origE);
    selfloop_mean_kernel<<<(N_NODES + 3) / 4, 256, 0, stream>>>(row, origE, ea, flag, lattr);

    const int GB = (N_NODES + 63) / 64;           // 782 row-blocks

    // ----- layer 1 (H=4, concat) -----
    gemm_mfma_kernel<128, 256, 0><<<GB, 256, 0, stream>>>(x, wf1, xs, flag, N_NODES);
    node_scores_kernel<4><<<(N_NODES + 3) / 4, 256, 0, stream>>>(xs, as1, ad1, flag, sA1, sD1);
    edge_pass_kernel<4><<<(N_EDGES + 255) / 256, 256, 0, stream>>>(srcS, dS, origE, ea, flag, M1, sA1, sD1, exw);
    self_pass_kernel<4><<<(N_NODES + 255) / 256, 256, 0, stream>>>(lattr, M1, sA1, sD1, exS);
    agg_fused_kernel<4, 1><<<(N_NODES + 3) / 4, 256, 0, stream>>>(row, srcS, xs, exw, exS, b1, flag, h1);

    // ----- layer 2 (H=2, mean) -----
    gemm_mfma_kernel<256, 128, 1><<<GB, 256, 0, stream>>>(h1, wf2, xs, flag, N_NODES);
    node_scores_kernel<2><<<(N_NODES + 3) / 4, 256, 0, stream>>>(xs, as2, ad2, flag, sA2, sD2);
    edge_pass_kernel<2><<<(N_EDGES + 255) / 256, 256, 0, stream>>>(srcS, dS, origE, ea, flag, M2, sA2, sD2, exw);
    self_pass_kernel<2><<<(N_NODES + 255) / 256, 256, 0, stream>>>(lattr, M2, sA2, sD2, exS);
    agg_fused_kernel<2, 2><<<(N_NODES + 3) / 4, 256, 0, stream>>>(row, srcS, xs, exw, exS, b2, flag, h2);

    // ----- pool + readout -----
    pool_max_kernel<<<N_GRAPHS, 256, 0, stream>>>(h2, batch, gpool);
    readout_kernel<<<N_GRAPHS, 64, 0, stream>>>(gpool, Wr, br, flag, d_out);
}

// Round 5
// 743.295 us; speedup vs baseline: 2.6399x; 1.0273x over previous
//
#include <hip/hip_runtime.h>
#include <hip/hip_bf16.h>

#define DEVINL __device__ __forceinline__
typedef __hip_bfloat16 bf16;

typedef __attribute__((ext_vector_type(8))) __bf16 bf16x8;
typedef __attribute__((ext_vector_type(4))) float f32x4;

static constexpr int N_NODES  = 50000;
static constexpr int N_EDGES  = 800000;
static constexpr int N_GRAPHS = 128;
static constexpr float NEG_SLOPE = 0.2f;

// Dual-path input load: isbf=1 -> storage is bf16, else fp32.
DEVINL float ldIn(const void* __restrict__ p, size_t i, int isbf) {
    if (isbf) return __bfloat162float(((const bf16*)p)[i]);
    return ((const float*)p)[i];
}

DEVINL unsigned short f2bf(float f) {
    bf16 b = __float2bfloat16(f);
    return *reinterpret_cast<unsigned short*>(&b);
}

DEVINL float bfu2f(unsigned short u) {           // bf16 bits -> f32 (shift only)
    return __uint_as_float(((unsigned)u) << 16);
}

// ---------- runtime dtype detection (see round-1 notes) ----------
__global__ void detect_dtype_kernel(const unsigned short* __restrict__ xu,
                                    int* __restrict__ flag)
{
    int t = threadIdx.x;
    int bad = 0;
    for (int i = t; i < 1024; i += 64) {
        unsigned u = xu[2 * i];
        float v = __uint_as_float(u << 16);
        if (!(fabsf(v) <= 1e4f)) bad = 1;
    }
    unsigned long long m = __ballot(bad);
    if (t == 0) *flag = m ? 0 : 1;          // 1 = bf16 storage
}

// ---------- tiny setup: M[d][h] = sum_c We[d, h*64+c] * a_e[h, c] ----------
__global__ void build_M_kernel(const void* __restrict__ We1, const void* __restrict__ ae1,
                               const void* __restrict__ We2, const void* __restrict__ ae2,
                               const int* __restrict__ flagp,
                               float* __restrict__ M1, float* __restrict__ M2)
{
    const int isbf = *flagp;
    int t = threadIdx.x;
    if (t < 64) {
        int d = t >> 2, h = t & 3;
        float s = 0.f;
        for (int c = 0; c < 64; ++c)
            s += ldIn(We1, d * 256 + h * 64 + c, isbf) * ldIn(ae1, h * 64 + c, isbf);
        M1[d * 4 + h] = s;
    }
    if (t < 32) {
        int d = t >> 1, h = t & 1;
        float s = 0.f;
        for (int c = 0; c < 64; ++c)
            s += ldIn(We2, d * 128 + h * 64 + c, isbf) * ldIn(ae2, h * 64 + c, isbf);
        M2[d * 2 + h] = s;
    }
}

// ---------- pack W[K,M] into MFMA B-fragment order ----------
template<int K, int M>
__global__ void build_wfrag_kernel(const void* __restrict__ W, const int* __restrict__ flagp,
                                   bf16* __restrict__ Wfrag)
{
    constexpr int KS = K / 32;
    const int isbf = *flagp;
    int idx = blockIdx.x * 256 + threadIdx.x;
    constexpr int total = (M / 16) * KS * 64 * 8;
    if (idx >= total) return;
    int j    = idx & 7;
    int lane = (idx >> 3) & 63;
    int rem  = idx >> 9;
    int ks   = rem % KS;
    int ct   = rem / KS;
    int k = ks * 32 + (lane >> 4) * 8 + j;
    int n = ct * 16 + (lane & 15);
    Wfrag[idx] = __float2bfloat16(ldIn(W, (size_t)k * M + n, isbf));
}

// ---------- MFMA GEMM: C[N,M] = A[N,K] @ W[K,M], C stored bf16 ----------
template<int K, int M, int AMODE>
__global__ __launch_bounds__(256)
void gemm_mfma_kernel(const void* __restrict__ A, const bf16* __restrict__ Wfrag,
                      bf16* __restrict__ C, const int* __restrict__ flagp, int N)
{
    constexpr int KS = K / 32, CT = M / 16;
    constexpr int LDA = K + 8;
    __shared__ __align__(16) unsigned short Asm[64 * LDA];
    const int isbf = *flagp;
    const int tid  = threadIdx.x;
    const int wave = tid >> 6, lane = tid & 63;
    const int n0 = blockIdx.x * 64;

    for (int i = tid; i < 64 * (K / 8); i += 256) {
        int r  = i / (K / 8);
        int kc = (i % (K / 8)) * 8;
        int n  = n0 + r;
        unsigned short v[8] = {0, 0, 0, 0, 0, 0, 0, 0};
        if (n < N) {
            size_t base = (size_t)n * K + kc;
            if (AMODE == 1 || isbf) {
                *reinterpret_cast<uint4*>(v) =
                    *reinterpret_cast<const uint4*>((const unsigned short*)A + base);
            } else {
                const float* Af = (const float*)A + base;
                float4 f0 = *reinterpret_cast<const float4*>(Af);
                float4 f1 = *reinterpret_cast<const float4*>(Af + 4);
                v[0] = f2bf(f0.x); v[1] = f2bf(f0.y); v[2] = f2bf(f0.z); v[3] = f2bf(f0.w);
                v[4] = f2bf(f1.x); v[5] = f2bf(f1.y); v[6] = f2bf(f1.z); v[7] = f2bf(f1.w);
            }
        }
        *reinterpret_cast<uint4*>(&Asm[r * LDA + kc]) = *reinterpret_cast<uint4*>(v);
    }
    __syncthreads();

    f32x4 acc[CT];
    #pragma unroll
    for (int ct = 0; ct < CT; ++ct) acc[ct] = (f32x4){0.f, 0.f, 0.f, 0.f};

    const int arow  = wave * 16 + (lane & 15);
    const int akoff = (lane >> 4) * 8;
    #pragma unroll
    for (int ks = 0; ks < KS; ++ks) {
        bf16x8 af = *reinterpret_cast<const bf16x8*>(&Asm[arow * LDA + ks * 32 + akoff]);
        #pragma unroll
        for (int ct = 0; ct < CT; ++ct) {
            bf16x8 bfr = *reinterpret_cast<const bf16x8*>(
                &Wfrag[(((size_t)ct * KS + ks) * 64 + lane) * 8]);
            acc[ct] = __builtin_amdgcn_mfma_f32_16x16x32_bf16(af, bfr, acc[ct], 0, 0, 0);
        }
    }

    const int crow0 = n0 + wave * 16 + (lane >> 4) * 4;
    const int ccol  = lane & 15;
    #pragma unroll
    for (int ct = 0; ct < CT; ++ct) {
        #pragma unroll
        for (int r = 0; r < 4; ++r) {
            int row = crow0 + r;
            if (row < N) C[(size_t)row * M + ct * 16 + ccol] = __float2bfloat16(acc[ct][r]);
        }
    }
}

// ---------- CSR build ----------
__global__ void csr_count_kernel(const int* __restrict__ dst, int* __restrict__ cnt)
{
    int e = blockIdx.x * blockDim.x + threadIdx.x;
    if (e >= N_EDGES) return;
    atomicAdd(&cnt[dst[e]], 1);
}

__global__ __launch_bounds__(1024)
void csr_scan_kernel(const int* __restrict__ cnt, int* __restrict__ row,
                     int* __restrict__ cursor)
{
    __shared__ int buf[1024];
    __shared__ int carry;
    int tid = threadIdx.x;
    if (tid == 0) carry = 0;
    __syncthreads();
    for (int base = 0; base < N_NODES; base += 1024) {
        int v = (base + tid < N_NODES) ? cnt[base + tid] : 0;
        buf[tid] = v;
        __syncthreads();
        for (int off = 1; off < 1024; off <<= 1) {
            int t = (tid >= off) ? buf[tid - off] : 0;
            __syncthreads();
            buf[tid] += t;
            __syncthreads();
        }
        int excl = buf[tid] - v + carry;
        if (base + tid < N_NODES) { row[base + tid] = excl; cursor[base + tid] = excl; }
        __syncthreads();
        if (tid == 0) carry += buf[1023];
        __syncthreads();
    }
    if (threadIdx.x == 0) row[N_NODES] = carry;
}

__global__ void csr_scatter_kernel(const int* __restrict__ srcI, const int* __restrict__ dstI,
                                   int* __restrict__ cursor, int* __restrict__ srcS,
                                   int* __restrict__ dS, int* __restrict__ origE)
{
    int e = blockIdx.x * blockDim.x + threadIdx.x;
    if (e >= N_EDGES) return;
    int d = dstI[e];
    int pos = atomicAdd(&cursor[d], 1);
    srcS[pos] = srcI[e];
    dS[pos] = d;
    origE[pos] = e;
}

// ---------- self-loop attr: per-dst mean via CSR gather ----------
__global__ __launch_bounds__(256)
void selfloop_mean_kernel(const int* __restrict__ row, const int* __restrict__ origE,
                          const void* __restrict__ eattr, const int* __restrict__ flagp,
                          float* __restrict__ lattr)
{
    const int isbf = *flagp;
    int d = (blockIdx.x * 256 + threadIdx.x) >> 6;
    int lane = threadIdx.x & 63;
    if (d >= N_NODES) return;
    int b = row[d], eend = row[d + 1];
    int cntv = eend - b;
    int k = lane & 15, g = lane >> 4;
    float s = 0.f;
    for (int j = b + g; j < eend; j += 4) {
        int e = origE[j];
        s += ldIn(eattr, (size_t)e * 16 + k, isbf);
    }
    s += __shfl_down(s, 32);
    s += __shfl_down(s, 16);
    if (lane < 16) lattr[(size_t)d * 16 + k] = s / fmaxf((float)cntv, 1.f);
}

// ---------- per-node attention logits: one wave per node ----------
template<int H>
__global__ __launch_bounds__(256)
void node_scores_kernel(const bf16* __restrict__ xs, const void* __restrict__ a_src,
                        const void* __restrict__ a_dst, const int* __restrict__ flagp,
                        float* __restrict__ sA, float* __restrict__ sD)
{
    const int isbf = *flagp;
    int wave = (blockIdx.x * 256 + threadIdx.x) >> 6;
    int lane = threadIdx.x & 63;
    if (wave >= N_NODES) return;
    #pragma unroll
    for (int h = 0; h < H; ++h) {
        float v  = __bfloat162float(xs[(size_t)wave * (H * 64) + h * 64 + lane]);
        float ps = v * ldIn(a_src, h * 64 + lane, isbf);
        float pd = v * ldIn(a_dst, h * 64 + lane, isbf);
        for (int off = 32; off; off >>= 1) {
            ps += __shfl_down(ps, off);
            pd += __shfl_down(pd, off);
        }
        if (lane == 0) { sA[wave * H + h] = ps; sD[wave * H + h] = pd; }
    }
}

// ---------- edge pass over SORTED edges ----------
template<int H>
__global__ void edge_pass_kernel(const int* __restrict__ srcS, const int* __restrict__ dS,
                                 const int* __restrict__ origE,
                                 const void* __restrict__ eattr, const int* __restrict__ flagp,
                                 const float* __restrict__ M,
                                 const float* __restrict__ sA, const float* __restrict__ sD,
                                 float* __restrict__ exw)
{
    const int isbf = *flagp;
    int j = blockIdx.x * blockDim.x + threadIdx.x;
    if (j >= N_EDGES) return;
    int e = origE[j], s = srcS[j], d = dS[j];
    float attr[16];
    #pragma unroll
    for (int k = 0; k < 16; ++k) attr[k] = ldIn(eattr, (size_t)e * 16 + k, isbf);
    #pragma unroll
    for (int h = 0; h < H; ++h) {
        float se = 0.f;
        #pragma unroll
        for (int k = 0; k < 16; ++k) se += attr[k] * M[k * H + h];
        float sc = sA[s * H + h] + sD[d * H + h] + se;
        sc = sc > 0.f ? sc : NEG_SLOPE * sc;
        exw[(size_t)j * H + h] = expf(sc);   // |sc| <~ 15, safe in fp32
    }
}

// ---------- self-loop edge pass ----------
template<int H>
__global__ void self_pass_kernel(const float* __restrict__ lattr, const float* __restrict__ M,
                                 const float* __restrict__ sA, const float* __restrict__ sD,
                                 float* __restrict__ exSelf)
{
    int n = blockIdx.x * blockDim.x + threadIdx.x;
    if (n >= N_NODES) return;
    float attr[16];
    #pragma unroll
    for (int k = 0; k < 16; ++k) attr[k] = lattr[(size_t)n * 16 + k];
    #pragma unroll
    for (int h = 0; h < H; ++h) {
        float se = 0.f;
        #pragma unroll
        for (int k = 0; k < 16; ++k) se += attr[k] * M[k * H + h];
        float sc = sA[n * H + h] + sD[n * H + h] + se;
        sc = sc > 0.f ? sc : NEG_SLOPE * sc;
        exSelf[(size_t)n * H + h] = expf(sc);
    }
}

// ---------- fused aggregation: one wave per dst node, lane = 64/H-channel group ----
// Lane covers H consecutive channels (all within head h = lane*H/64), so the
// xs row slice is one vector load and the softmax weight is one scalar.
// LAYER 1 (H=4): out = relu(agg + b1) -> bf16 h1[N,256]
// LAYER 2 (H=2): out = mean_heads(agg) + b2 -> fp32 h2[N,64]
template<int H, int LAYER>
__global__ __launch_bounds__(256)
void agg_fused_kernel(const int* __restrict__ row, const int* __restrict__ srcS,
                      const bf16* __restrict__ xs, const float* __restrict__ exw,
                      const float* __restrict__ exSelf, const void* __restrict__ bias,
                      const int* __restrict__ flagp, void* __restrict__ out)
{
    const int isbf = *flagp;
    const int d = (blockIdx.x * 256 + threadIdx.x) >> 6;
    const int lane = threadIdx.x & 63;
    if (d >= N_NODES) return;
    const int h = (lane * H) >> 6;                    // this lane's head
    const unsigned short* xsu = (const unsigned short*)xs;

    float acc[H];
    float den;
    {   // self loop
        float w = exSelf[(size_t)d * H + h];
        den = w;
        unsigned short v[H];
        *reinterpret_cast<uint2*>(v) = (H == 4)
            ? *reinterpret_cast<const uint2*>(&xsu[(size_t)d * (H * 64) + lane * H])
            : (uint2){0, 0};
        if (H == 2)
            *reinterpret_cast<unsigned*>(v) =
                *reinterpret_cast<const unsigned*>(&xsu[(size_t)d * (H * 64) + lane * H]);
        #pragma unroll
        for (int i = 0; i < H; ++i) acc[i] = w * bfu2f(v[i]);
    }

    const int b = row[d], eend = row[d + 1];
    for (int j = b; j < eend; ++j) {
        int s = srcS[j];
        float w = exw[(size_t)j * H + h];             // 16B broadcast per wave
        unsigned short v[H];
        if (H == 4)
            *reinterpret_cast<uint2*>(v) =
                *reinterpret_cast<const uint2*>(&xsu[(size_t)s * (H * 64) + lane * H]);
        else
            *reinterpret_cast<unsigned*>(v) =
                *reinterpret_cast<const unsigned*>(&xsu[(size_t)s * (H * 64) + lane * H]);
        den += w;
        #pragma unroll
        for (int i = 0; i < H; ++i) acc[i] += w * bfu2f(v[i]);
    }

    const float rden = 1.f / (den + 1e-16f);
    if (LAYER == 1) {
        unsigned short o[H];
        #pragma unroll
        for (int i = 0; i < H; ++i) {
            float v = acc[i] * rden + ldIn(bias, lane * H + i, isbf);
            o[i] = f2bf(v > 0.f ? v : 0.f);
        }
        *reinterpret_cast<uint2*>(&((unsigned short*)out)[(size_t)d * (H * 64) + lane * H]) =
            *reinterpret_cast<uint2*>(o);
    } else {
        // lane (<32): channels {2*lane, 2*lane+1} head0; lane+32 has same channels head1
        float v0 = acc[0] * rden, v1 = acc[1] * rden;
        float p0 = __shfl(v0, lane + 32), p1 = __shfl(v1, lane + 32);
        if (lane < 32) {
            float2 o;
            o.x = 0.5f * (v0 + p0) + ldIn(bias, lane * 2 + 0, isbf);
            o.y = 0.5f * (v1 + p1) + ldIn(bias, lane * 2 + 1, isbf);
            *reinterpret_cast<float2*>(&((float*)out)[(size_t)d * 64 + lane * 2]) = o;
        }
    }
}

// ---------- pooling ----------
__global__ __launch_bounds__(256)
void pool_max_kernel(const float* __restrict__ h2, const int* __restrict__ batch,
                     float* __restrict__ g)
{
    int gi = blockIdx.x;
    int lo = 0, hi = N_NODES;
    while (lo < hi) { int mid = (lo + hi) >> 1; if (batch[mid] < gi) lo = mid + 1; else hi = mid; }
    int start = lo;
    lo = start; hi = N_NODES;
    while (lo < hi) { int mid = (lo + hi) >> 1; if (batch[mid] < gi + 1) lo = mid + 1; else hi = mid; }
    int end = lo;
    int c = threadIdx.x & 63, chunk = threadIdx.x >> 6;
    float m = -INFINITY;
    for (int n = start + chunk; n < end; n += 4) m = fmaxf(m, h2[(size_t)n * 64 + c]);
    __shared__ float sm[256];
    sm[threadIdx.x] = m;
    __syncthreads();
    if (threadIdx.x < 64) {
        m = fmaxf(fmaxf(sm[threadIdx.x], sm[threadIdx.x + 64]),
                  fmaxf(sm[threadIdx.x + 128], sm[threadIdx.x + 192]));
        g[gi * 64 + threadIdx.x] = m;
    }
}

// ---------- readout ----------
__global__ void readout_kernel(const float* __restrict__ g, const void* __restrict__ Wr,
                               const void* __restrict__ br, const int* __restrict__ flagp,
                               void* __restrict__ out)
{
    const int isbf = *flagp;
    int gi = blockIdx.x;
    int lane = threadIdx.x;
    float p = g[gi * 64 + lane] * ldIn(Wr, lane, isbf);
    for (int off = 32; off; off >>= 1) p += __shfl_down(p, off);
    if (lane == 0) {
        float r = p + ldIn(br, 0, isbf);
        if (isbf) ((bf16*)out)[gi] = __float2bfloat16(r);
        else      ((float*)out)[gi] = r;
    }
}

extern "C" void kernel_launch(void* const* d_in, const int* in_sizes, int n_in,
                              void* d_out, int out_size, void* d_ws, size_t ws_size,
                              hipStream_t stream)
{
    const void* x     = d_in[0];
    const void* ea    = d_in[1];
    const int*  eidx  = (const int*)d_in[2];
    const int*  batch = (const int*)d_in[3];
    const void* W1  = d_in[4];
    const void* as1 = d_in[5];
    const void* ad1 = d_in[6];
    const void* We1 = d_in[7];
    const void* ae1 = d_in[8];
    const void* b1  = d_in[9];
    const void* W2  = d_in[10];
    const void* as2 = d_in[11];
    const void* ad2 = d_in[12];
    const void* We2 = d_in[13];
    const void* ae2 = d_in[14];
    const void* b2  = d_in[15];
    const void* Wr  = d_in[16];
    const void* br  = d_in[17];

    const int* srcI = eidx;
    const int* dstI = eidx + N_EDGES;

    // ---- workspace layout (float-index offsets), peak ~81 MB ----
    float* ws    = (float*)d_ws;
    bf16*  xs    = (bf16*)ws;                     // [0, 6.4M): N*256 bf16 (L2: N*128 bf16)
    bf16*  h1    = (bf16*)(ws + 6400000);         // [6.4M, 12.8M): N*256 bf16
    float* h2    = ws + 6400000;                  // N*64 fp32, overlays h1 (dead after gemm2)
    float* exw   = ws + 12800000;                 // E*4 fp32 (L2 uses E*2)
    float* exS   = ws + 16000000;                 // N*4
    float* sA1   = ws + 16200000;                 // N*4
    float* sD1   = ws + 16400000;                 // N*4
    float* sA2   = ws + 16600000;                 // N*2
    float* sD2   = ws + 16700000;                 // N*2
    float* lattr = ws + 16800000;                 // N*16
    int*   ib    = (int*)(ws + 17600000);         // int region
    int*   row    = ib;                           // N+1
    int*   cursor = ib + 50016;                   // N
    int*   cnt    = ib + 100032;                  // N
    int*   srcS   = ib + 150048;                  // E
    int*   dS     = ib + 950048;                  // E
    int*   origE  = ib + 1750048;                 // E
    float* misc  = ws + 17600000 + 2550048;
    int*   flag  = (int*)misc;                    // 1
    float* M1    = misc + 16;                     // 64
    float* M2    = misc + 80;                     // 32
    float* gpool = misc + 112;                    // 128*64
    bf16*  wf1   = (bf16*)(misc + 8320);          // 32768 bf16
    bf16*  wf2   = (bf16*)(misc + 8320 + 16384);  // 32768 bf16

    hipMemsetAsync(cnt, 0, N_NODES * sizeof(int), stream);

    detect_dtype_kernel<<<1, 64, 0, stream>>>((const unsigned short*)x, flag);
    build_M_kernel<<<1, 64, 0, stream>>>(We1, ae1, We2, ae2, flag, M1, M2);
    build_wfrag_kernel<128, 256><<<128, 256, 0, stream>>>(W1, flag, wf1);
    build_wfrag_kernel<256, 128><<<128, 256, 0, stream>>>(W2, flag, wf2);

    // ----- CSR over dst -----
    csr_count_kernel<<<(N_EDGES + 255) / 256, 256, 0, stream>>>(dstI, cnt);
    csr_scan_kernel<<<1, 1024, 0, stream>>>(cnt, row, cursor);
    csr_scatter_kernel<<<(N_EDGES + 255) / 256, 256, 0, stream>>>(srcI, dstI, cursor, srcS, dS, origE);
    selfloop_mean_kernel<<<(N_NODES + 3) / 4, 256, 0, stream>>>(row, origE, ea, flag, lattr);

    const int GB = (N_NODES + 63) / 64;           // 782 row-blocks

    // ----- layer 1 (H=4, concat) -----
    gemm_mfma_kernel<128, 256, 0><<<GB, 256, 0, stream>>>(x, wf1, xs, flag, N_NODES);
    node_scores_kernel<4><<<(N_NODES + 3) / 4, 256, 0, stream>>>(xs, as1, ad1, flag, sA1, sD1);
    edge_pass_kernel<4><<<(N_EDGES + 255) / 256, 256, 0, stream>>>(srcS, dS, origE, ea, flag, M1, sA1, sD1, exw);
    self_pass_kernel<4><<<(N_NODES + 255) / 256, 256, 0, stream>>>(lattr, M1, sA1, sD1, exS);
    agg_fused_kernel<4, 1><<<(N_NODES + 3) / 4, 256, 0, stream>>>(row, srcS, xs, exw, exS, b1, flag, h1);

    // ----- layer 2 (H=2, mean) -----
    gemm_mfma_kernel<256, 128, 1><<<GB, 256, 0, stream>>>(h1, wf2, xs, flag, N_NODES);
    node_scores_kernel<2><<<(N_NODES + 3) / 4, 256, 0, stream>>>(xs, as2, ad2, flag, sA2, sD2);
    edge_pass_kernel<2><<<(N_EDGES + 255) / 256, 256, 0, stream>>>(srcS, dS, origE, ea, flag, M2, sA2, sD2, exw);
    self_pass_kernel<2><<<(N_NODES + 255) / 256, 256, 0, stream>>>(lattr, M2, sA2, sD2, exS);
    agg_fused_kernel<2, 2><<<(N_NODES + 3) / 4, 256, 0, stream>>>(row, srcS, xs, exw, exS, b2, flag, h2);

    // ----- pool + readout -----
    pool_max_kernel<<<N_GRAPHS, 256, 0, stream>>>(h2, batch, gpool);
    readout_kernel<<<N_GRAPHS, 64, 0, stream>>>(gpool, Wr, br, flag, d_out);
}

// Round 6
// 540.390 us; speedup vs baseline: 3.6311x; 1.3755x over previous
//
#include <hip/hip_runtime.h>
#include <hip/hip_bf16.h>

#define DEVINL __device__ __forceinline__
typedef __hip_bfloat16 bf16;

typedef __attribute__((ext_vector_type(8))) __bf16 bf16x8;
typedef __attribute__((ext_vector_type(4))) float f32x4;

static constexpr int N_NODES  = 50000;
static constexpr int N_EDGES  = 800000;
static constexpr int N_GRAPHS = 128;
static constexpr float NEG_SLOPE = 0.2f;

// Dual-path input load: isbf=1 -> storage is bf16, else fp32.
DEVINL float ldIn(const void* __restrict__ p, size_t i, int isbf) {
    if (isbf) return __bfloat162float(((const bf16*)p)[i]);
    return ((const float*)p)[i];
}

DEVINL unsigned short f2bf(float f) {
    bf16 b = __float2bfloat16(f);
    return *reinterpret_cast<unsigned short*>(&b);
}

DEVINL float bfu2f(unsigned short u) {           // bf16 bits -> f32 (shift only)
    return __uint_as_float(((unsigned)u) << 16);
}

template<int H>
DEVINL void ldrow(const unsigned short* __restrict__ p, unsigned short (&v)[H]) {
    if (H == 4) *reinterpret_cast<uint2*>(v)    = *reinterpret_cast<const uint2*>(p);
    else        *reinterpret_cast<unsigned*>(v) = *reinterpret_cast<const unsigned*>(p);
}

DEVINL float lrelu_exp(float sc) {
    sc = sc > 0.f ? sc : NEG_SLOPE * sc;
    return __expf(sc);
}

// ---------- runtime dtype detection (see round-1 notes) ----------
__global__ void detect_dtype_kernel(const unsigned short* __restrict__ xu,
                                    int* __restrict__ flag)
{
    int t = threadIdx.x;
    int bad = 0;
    for (int i = t; i < 1024; i += 64) {
        unsigned u = xu[2 * i];
        float v = __uint_as_float(u << 16);
        if (!(fabsf(v) <= 1e4f)) bad = 1;
    }
    unsigned long long m = __ballot(bad);
    if (t == 0) *flag = m ? 0 : 1;          // 1 = bf16 storage
}

// ---------- tiny setup: M[d][h] = sum_c We[d, h*64+c] * a_e[h, c] ----------
__global__ void build_M_kernel(const void* __restrict__ We1, const void* __restrict__ ae1,
                               const void* __restrict__ We2, const void* __restrict__ ae2,
                               const int* __restrict__ flagp,
                               float* __restrict__ M1, float* __restrict__ M2)
{
    const int isbf = *flagp;
    int t = threadIdx.x;
    if (t < 64) {
        int d = t >> 2, h = t & 3;
        float s = 0.f;
        for (int c = 0; c < 64; ++c)
            s += ldIn(We1, d * 256 + h * 64 + c, isbf) * ldIn(ae1, h * 64 + c, isbf);
        M1[d * 4 + h] = s;
    }
    if (t < 32) {
        int d = t >> 1, h = t & 1;
        float s = 0.f;
        for (int c = 0; c < 64; ++c)
            s += ldIn(We2, d * 128 + h * 64 + c, isbf) * ldIn(ae2, h * 64 + c, isbf);
        M2[d * 2 + h] = s;
    }
}

// ---------- pack W[K,M] into MFMA B-fragment order ----------
template<int K, int M>
__global__ void build_wfrag_kernel(const void* __restrict__ W, const int* __restrict__ flagp,
                                   bf16* __restrict__ Wfrag)
{
    constexpr int KS = K / 32;
    const int isbf = *flagp;
    int idx = blockIdx.x * 256 + threadIdx.x;
    constexpr int total = (M / 16) * KS * 64 * 8;
    if (idx >= total) return;
    int j    = idx & 7;
    int lane = (idx >> 3) & 63;
    int rem  = idx >> 9;
    int ks   = rem % KS;
    int ct   = rem / KS;
    int k = ks * 32 + (lane >> 4) * 8 + j;
    int n = ct * 16 + (lane & 15);
    Wfrag[idx] = __float2bfloat16(ldIn(W, (size_t)k * M + n, isbf));
}

// ---------- MFMA GEMM: C[N,M] = A[N,K] @ W[K,M], C stored bf16 ----------
template<int K, int M, int AMODE>
__global__ __launch_bounds__(256)
void gemm_mfma_kernel(const void* __restrict__ A, const bf16* __restrict__ Wfrag,
                      bf16* __restrict__ C, const int* __restrict__ flagp, int N)
{
    constexpr int KS = K / 32, CT = M / 16;
    constexpr int LDA = K + 8;
    __shared__ __align__(16) unsigned short Asm[64 * LDA];
    const int isbf = *flagp;
    const int tid  = threadIdx.x;
    const int wave = tid >> 6, lane = tid & 63;
    const int n0 = blockIdx.x * 64;

    for (int i = tid; i < 64 * (K / 8); i += 256) {
        int r  = i / (K / 8);
        int kc = (i % (K / 8)) * 8;
        int n  = n0 + r;
        unsigned short v[8] = {0, 0, 0, 0, 0, 0, 0, 0};
        if (n < N) {
            size_t base = (size_t)n * K + kc;
            if (AMODE == 1 || isbf) {
                *reinterpret_cast<uint4*>(v) =
                    *reinterpret_cast<const uint4*>((const unsigned short*)A + base);
            } else {
                const float* Af = (const float*)A + base;
                float4 f0 = *reinterpret_cast<const float4*>(Af);
                float4 f1 = *reinterpret_cast<const float4*>(Af + 4);
                v[0] = f2bf(f0.x); v[1] = f2bf(f0.y); v[2] = f2bf(f0.z); v[3] = f2bf(f0.w);
                v[4] = f2bf(f1.x); v[5] = f2bf(f1.y); v[6] = f2bf(f1.z); v[7] = f2bf(f1.w);
            }
        }
        *reinterpret_cast<uint4*>(&Asm[r * LDA + kc]) = *reinterpret_cast<uint4*>(v);
    }
    __syncthreads();

    f32x4 acc[CT];
    #pragma unroll
    for (int ct = 0; ct < CT; ++ct) acc[ct] = (f32x4){0.f, 0.f, 0.f, 0.f};

    const int arow  = wave * 16 + (lane & 15);
    const int akoff = (lane >> 4) * 8;
    #pragma unroll
    for (int ks = 0; ks < KS; ++ks) {
        bf16x8 af = *reinterpret_cast<const bf16x8*>(&Asm[arow * LDA + ks * 32 + akoff]);
        #pragma unroll
        for (int ct = 0; ct < CT; ++ct) {
            bf16x8 bfr = *reinterpret_cast<const bf16x8*>(
                &Wfrag[(((size_t)ct * KS + ks) * 64 + lane) * 8]);
            acc[ct] = __builtin_amdgcn_mfma_f32_16x16x32_bf16(af, bfr, acc[ct], 0, 0, 0);
        }
    }

    const int crow0 = n0 + wave * 16 + (lane >> 4) * 4;
    const int ccol  = lane & 15;
    #pragma unroll
    for (int ct = 0; ct < CT; ++ct) {
        #pragma unroll
        for (int r = 0; r < 4; ++r) {
            int row = crow0 + r;
            if (row < N) C[(size_t)row * M + ct * 16 + ccol] = __float2bfloat16(acc[ct][r]);
        }
    }
}

// ---------- CSR build ----------
__global__ void csr_count_kernel(const int* __restrict__ dst, int* __restrict__ cnt)
{
    int e = blockIdx.x * blockDim.x + threadIdx.x;
    if (e >= N_EDGES) return;
    atomicAdd(&cnt[dst[e]], 1);
}

// per-256-chunk sums
__global__ __launch_bounds__(256)
void scan_sum_kernel(const int* __restrict__ cnt, int* __restrict__ bsum)
{
    __shared__ int sm[256];
    int i = blockIdx.x * 256 + threadIdx.x;
    sm[threadIdx.x] = (i < N_NODES) ? cnt[i] : 0;
    __syncthreads();
    for (int off = 128; off; off >>= 1) {
        if (threadIdx.x < off) sm[threadIdx.x] += sm[threadIdx.x + off];
        __syncthreads();
    }
    if (threadIdx.x == 0) bsum[blockIdx.x] = sm[0];
}

// single-block exclusive scan of bsum[nb] in place (nb <= 256)
__global__ __launch_bounds__(256)
void scan_off_kernel(int* __restrict__ bsum, int nb)
{
    __shared__ int sm[256];
    int tid = threadIdx.x;
    int v = (tid < nb) ? bsum[tid] : 0;
    sm[tid] = v;
    __syncthreads();
    for (int off = 1; off < 256; off <<= 1) {
        int t = (tid >= off) ? sm[tid - off] : 0;
        __syncthreads();
        sm[tid] += t;
        __syncthreads();
    }
    if (tid < nb) bsum[tid] = sm[tid] - v;
}

__global__ __launch_bounds__(256)
void scan_final_kernel(const int* __restrict__ cnt, const int* __restrict__ bsum,
                       int* __restrict__ row, int* __restrict__ cursor)
{
    __shared__ int sm[256];
    int i = blockIdx.x * 256 + threadIdx.x;
    int tid = threadIdx.x;
    int v = (i < N_NODES) ? cnt[i] : 0;
    sm[tid] = v;
    __syncthreads();
    for (int off = 1; off < 256; off <<= 1) {
        int t = (tid >= off) ? sm[tid - off] : 0;
        __syncthreads();
        sm[tid] += t;
        __syncthreads();
    }
    int excl = sm[tid] - v + bsum[blockIdx.x];
    if (i < N_NODES) { row[i] = excl; cursor[i] = excl; }
    if (i == N_NODES - 1) row[N_NODES] = excl + v;
}

__global__ void csr_scatter_kernel(const int* __restrict__ srcI, const int* __restrict__ dstI,
                                   int* __restrict__ cursor, int* __restrict__ srcS,
                                   int* __restrict__ origE)
{
    int e = blockIdx.x * blockDim.x + threadIdx.x;
    if (e >= N_EDGES) return;
    int d = dstI[e];
    int pos = atomicAdd(&cursor[d], 1);
    srcS[pos] = srcI[e];
    origE[pos] = e;
}

// ---------- self-loop attr: per-dst mean via CSR gather ----------
__global__ __launch_bounds__(256)
void selfloop_mean_kernel(const int* __restrict__ row, const int* __restrict__ origE,
                          const void* __restrict__ eattr, const int* __restrict__ flagp,
                          float* __restrict__ lattr)
{
    const int isbf = *flagp;
    int d = (blockIdx.x * 256 + threadIdx.x) >> 6;
    int lane = threadIdx.x & 63;
    if (d >= N_NODES) return;
    int b = row[d], eend = row[d + 1];
    int cntv = eend - b;
    int k = lane & 15, g = lane >> 4;
    float s = 0.f;
    for (int j = b + g; j < eend; j += 4) {
        int e = origE[j];
        s += ldIn(eattr, (size_t)e * 16 + k, isbf);
    }
    s += __shfl_down(s, 32);
    s += __shfl_down(s, 16);
    if (lane < 16) lattr[(size_t)d * 16 + k] = s / fmaxf((float)cntv, 1.f);
}

// ---------- per-edge attr projection, BOTH layers in one pass ----------
__global__ void se_pass_kernel(const int* __restrict__ origE, const void* __restrict__ eattr,
                               const int* __restrict__ flagp,
                               const float* __restrict__ M1, const float* __restrict__ M2,
                               float* __restrict__ se1, float* __restrict__ se2)
{
    const int isbf = *flagp;
    int j = blockIdx.x * blockDim.x + threadIdx.x;
    if (j >= N_EDGES) return;
    int e = origE[j];
    float attr[16];
    #pragma unroll
    for (int k = 0; k < 16; ++k) attr[k] = ldIn(eattr, (size_t)e * 16 + k, isbf);
    float4 o1 = {0.f, 0.f, 0.f, 0.f};
    float2 o2 = {0.f, 0.f};
    #pragma unroll
    for (int k = 0; k < 16; ++k) {
        o1.x += attr[k] * M1[k * 4 + 0];
        o1.y += attr[k] * M1[k * 4 + 1];
        o1.z += attr[k] * M1[k * 4 + 2];
        o1.w += attr[k] * M1[k * 4 + 3];
        o2.x += attr[k] * M2[k * 2 + 0];
        o2.y += attr[k] * M2[k * 2 + 1];
    }
    *reinterpret_cast<float4*>(&se1[(size_t)j * 4]) = o1;
    *reinterpret_cast<float2*>(&se2[(size_t)j * 2]) = o2;
}

// ---------- per-node attention logits: one wave per node ----------
template<int H>
__global__ __launch_bounds__(256)
void node_scores_kernel(const bf16* __restrict__ xs, const void* __restrict__ a_src,
                        const void* __restrict__ a_dst, const int* __restrict__ flagp,
                        float* __restrict__ sA, float* __restrict__ sD)
{
    const int isbf = *flagp;
    int wave = (blockIdx.x * 256 + threadIdx.x) >> 6;
    int lane = threadIdx.x & 63;
    if (wave >= N_NODES) return;
    #pragma unroll
    for (int h = 0; h < H; ++h) {
        float v  = __bfloat162float(xs[(size_t)wave * (H * 64) + h * 64 + lane]);
        float ps = v * ldIn(a_src, h * 64 + lane, isbf);
        float pd = v * ldIn(a_dst, h * 64 + lane, isbf);
        for (int off = 32; off; off >>= 1) {
            ps += __shfl_down(ps, off);
            pd += __shfl_down(pd, off);
        }
        if (lane == 0) { sA[wave * H + h] = ps; sD[wave * H + h] = pd; }
    }
}

// ---------- self-loop score: exp(leaky(sA+sD+se_self)) per node ----------
template<int H>
__global__ void self_pass_kernel(const float* __restrict__ lattr, const float* __restrict__ M,
                                 const float* __restrict__ sA, const float* __restrict__ sD,
                                 float* __restrict__ exSelf)
{
    int n = blockIdx.x * blockDim.x + threadIdx.x;
    if (n >= N_NODES) return;
    float attr[16];
    #pragma unroll
    for (int k = 0; k < 16; ++k) attr[k] = lattr[(size_t)n * 16 + k];
    #pragma unroll
    for (int h = 0; h < H; ++h) {
        float se = 0.f;
        #pragma unroll
        for (int k = 0; k < 16; ++k) se += attr[k] * M[k * H + h];
        exSelf[(size_t)n * H + h] = lrelu_exp(sA[n * H + h] + sD[n * H + h] + se);
    }
}

// ---------- fused score+softmax+aggregate: one wave per dst, lane = chan group ----
// w_j = exp(leaky(sA[s_j] + sD[d] + se[j])) computed inline; unroll x4 for MLP.
// LAYER 1 (H=4): out = relu(agg + b1) -> bf16 h1[N,256]
// LAYER 2 (H=2): out = mean_heads(agg) + b2 -> fp32 h2[N,64]
template<int H, int LAYER>
__global__ __launch_bounds__(256)
void agg_fused_kernel(const int* __restrict__ row, const int* __restrict__ srcS,
                      const bf16* __restrict__ xs, const float* __restrict__ seE,
                      const float* __restrict__ sA, const float* __restrict__ sD,
                      const float* __restrict__ exSelf, const void* __restrict__ bias,
                      const int* __restrict__ flagp, void* __restrict__ out)
{
    const int isbf = *flagp;
    const int d = (blockIdx.x * 256 + threadIdx.x) >> 6;
    const int lane = threadIdx.x & 63;
    if (d >= N_NODES) return;
    const int h = (lane * H) >> 6;                    // this lane's head
    const unsigned short* xsu = (const unsigned short*)xs;
    const float sDv = sD[(size_t)d * H + h];

    float acc[H];
    float den;
    {   // self loop
        float w = exSelf[(size_t)d * H + h];
        den = w;
        unsigned short v[H];
        ldrow<H>(&xsu[(size_t)d * (H * 64) + lane * H], v);
        #pragma unroll
        for (int i = 0; i < H; ++i) acc[i] = w * bfu2f(v[i]);
    }

    const int b = row[d], eend = row[d + 1];
    int j = b;
    for (; j + 3 < eend; j += 4) {
        // issue all independent loads first -> 4 gathers in flight
        const int s0 = srcS[j], s1 = srcS[j + 1], s2 = srcS[j + 2], s3 = srcS[j + 3];
        const float e0 = seE[(size_t)(j + 0) * H + h];
        const float e1 = seE[(size_t)(j + 1) * H + h];
        const float e2 = seE[(size_t)(j + 2) * H + h];
        const float e3 = seE[(size_t)(j + 3) * H + h];
        const float a0 = sA[(size_t)s0 * H + h];
        const float a1 = sA[(size_t)s1 * H + h];
        const float a2 = sA[(size_t)s2 * H + h];
        const float a3 = sA[(size_t)s3 * H + h];
        unsigned short v0[H], v1[H], v2[H], v3[H];
        ldrow<H>(&xsu[(size_t)s0 * (H * 64) + lane * H], v0);
        ldrow<H>(&xsu[(size_t)s1 * (H * 64) + lane * H], v1);
        ldrow<H>(&xsu[(size_t)s2 * (H * 64) + lane * H], v2);
        ldrow<H>(&xsu[(size_t)s3 * (H * 64) + lane * H], v3);
        const float w0 = lrelu_exp(a0 + sDv + e0);
        const float w1 = lrelu_exp(a1 + sDv + e1);
        const float w2 = lrelu_exp(a2 + sDv + e2);
        const float w3 = lrelu_exp(a3 + sDv + e3);
        den += (w0 + w1) + (w2 + w3);
        #pragma unroll
        for (int i = 0; i < H; ++i)
            acc[i] += w0 * bfu2f(v0[i]) + w1 * bfu2f(v1[i])
                    + w2 * bfu2f(v2[i]) + w3 * bfu2f(v3[i]);
    }
    for (; j < eend; ++j) {
        const int s = srcS[j];
        const float se = seE[(size_t)j * H + h];
        const float sa = sA[(size_t)s * H + h];
        unsigned short v[H];
        ldrow<H>(&xsu[(size_t)s * (H * 64) + lane * H], v);
        const float w = lrelu_exp(sa + sDv + se);
        den += w;
        #pragma unroll
        for (int i = 0; i < H; ++i) acc[i] += w * bfu2f(v[i]);
    }

    const float rden = 1.f / (den + 1e-16f);
    if (LAYER == 1) {
        unsigned short o[H];
        #pragma unroll
        for (int i = 0; i < H; ++i) {
            float v = acc[i] * rden + ldIn(bias, lane * H + i, isbf);
            o[i] = f2bf(v > 0.f ? v : 0.f);
        }
        *reinterpret_cast<uint2*>(&((unsigned short*)out)[(size_t)d * (H * 64) + lane * H]) =
            *reinterpret_cast<uint2*>(o);
    } else {
        // lane (<32): channels {2*lane, 2*lane+1} head0; lane+32 same channels head1
        float v0 = acc[0] * rden, v1 = acc[1] * rden;
        float p0 = __shfl(v0, lane + 32), p1 = __shfl(v1, lane + 32);
        if (lane < 32) {
            float2 o;
            o.x = 0.5f * (v0 + p0) + ldIn(bias, lane * 2 + 0, isbf);
            o.y = 0.5f * (v1 + p1) + ldIn(bias, lane * 2 + 1, isbf);
            *reinterpret_cast<float2*>(&((float*)out)[(size_t)d * 64 + lane * 2]) = o;
        }
    }
}

// ---------- pooling ----------
__global__ __launch_bounds__(256)
void pool_max_kernel(const float* __restrict__ h2, const int* __restrict__ batch,
                     float* __restrict__ g)
{
    int gi = blockIdx.x;
    int lo = 0, hi = N_NODES;
    while (lo < hi) { int mid = (lo + hi) >> 1; if (batch[mid] < gi) lo = mid + 1; else hi = mid; }
    int start = lo;
    lo = start; hi = N_NODES;
    while (lo < hi) { int mid = (lo + hi) >> 1; if (batch[mid] < gi + 1) lo = mid + 1; else hi = mid; }
    int end = lo;
    int c = threadIdx.x & 63, chunk = threadIdx.x >> 6;
    float m = -INFINITY;
    for (int n = start + chunk; n < end; n += 4) m = fmaxf(m, h2[(size_t)n * 64 + c]);
    __shared__ float sm[256];
    sm[threadIdx.x] = m;
    __syncthreads();
    if (threadIdx.x < 64) {
        m = fmaxf(fmaxf(sm[threadIdx.x], sm[threadIdx.x + 64]),
                  fmaxf(sm[threadIdx.x + 128], sm[threadIdx.x + 192]));
        g[gi * 64 + threadIdx.x] = m;
    }
}

// ---------- readout ----------
__global__ void readout_kernel(const float* __restrict__ g, const void* __restrict__ Wr,
                               const void* __restrict__ br, const int* __restrict__ flagp,
                               void* __restrict__ out)
{
    const int isbf = *flagp;
    int gi = blockIdx.x;
    int lane = threadIdx.x;
    float p = g[gi * 64 + lane] * ldIn(Wr, lane, isbf);
    for (int off = 32; off; off >>= 1) p += __shfl_down(p, off);
    if (lane == 0) {
        float r = p + ldIn(br, 0, isbf);
        if (isbf) ((bf16*)out)[gi] = __float2bfloat16(r);
        else      ((float*)out)[gi] = r;
    }
}

extern "C" void kernel_launch(void* const* d_in, const int* in_sizes, int n_in,
                              void* d_out, int out_size, void* d_ws, size_t ws_size,
                              hipStream_t stream)
{
    const void* x     = d_in[0];
    const void* ea    = d_in[1];
    const int*  eidx  = (const int*)d_in[2];
    const int*  batch = (const int*)d_in[3];
    const void* W1  = d_in[4];
    const void* as1 = d_in[5];
    const void* ad1 = d_in[6];
    const void* We1 = d_in[7];
    const void* ae1 = d_in[8];
    const void* b1  = d_in[9];
    const void* W2  = d_in[10];
    const void* as2 = d_in[11];
    const void* ad2 = d_in[12];
    const void* We2 = d_in[13];
    const void* ae2 = d_in[14];
    const void* b2  = d_in[15];
    const void* Wr  = d_in[16];
    const void* br  = d_in[17];

    const int* srcI = eidx;
    const int* dstI = eidx + N_EDGES;

    // ---- workspace layout (float-index offsets), peak ~84 MB ----
    float* ws    = (float*)d_ws;
    bf16*  xs    = (bf16*)ws;                     // [0, 6.4M): N*256 bf16 (L2: N*128)
    bf16*  h1    = (bf16*)(ws + 6400000);         // N*256 bf16
    float* h2    = ws + 6400000;                  // N*64 fp32 overlay (h1 dead after gemm2)
    float* se1   = ws + 12800000;                 // E*4
    float* se2   = ws + 16000000;                 // E*2
    float* exS   = ws + 17600000;                 // N*4
    float* sA1   = ws + 17800000;                 // N*4
    float* sD1   = ws + 18000000;                 // N*4
    float* sA2   = ws + 18200000;                 // N*2
    float* sD2   = ws + 18300000;                 // N*2
    float* lattr = ws + 18400000;                 // N*16
    int*   ib    = (int*)(ws + 19200000);
    int*   row    = ib;                           // N+1
    int*   cursor = ib + 50016;                   // N
    int*   cnt    = ib + 100032;                  // N
    int*   bsum   = ib + 150048;                  // 256
    int*   srcS   = ib + 150400;                  // E
    int*   origE  = ib + 950400;                  // E
    float* misc  = ws + 19200000 + 1750400;
    int*   flag  = (int*)misc;                    // 1
    float* M1    = misc + 16;                     // 64
    float* M2    = misc + 80;                     // 32
    float* gpool = misc + 112;                    // 128*64
    bf16*  wf1   = (bf16*)(misc + 8320);          // 32768 bf16
    bf16*  wf2   = (bf16*)(misc + 8320 + 16384);  // 32768 bf16

    hipMemsetAsync(cnt, 0, N_NODES * sizeof(int), stream);

    detect_dtype_kernel<<<1, 64, 0, stream>>>((const unsigned short*)x, flag);
    build_M_kernel<<<1, 64, 0, stream>>>(We1, ae1, We2, ae2, flag, M1, M2);
    build_wfrag_kernel<128, 256><<<128, 256, 0, stream>>>(W1, flag, wf1);
    build_wfrag_kernel<256, 128><<<128, 256, 0, stream>>>(W2, flag, wf2);

    // ----- CSR over dst (parallel scan) -----
    const int NB = (N_NODES + 255) / 256;         // 196
    csr_count_kernel<<<(N_EDGES + 255) / 256, 256, 0, stream>>>(dstI, cnt);
    scan_sum_kernel<<<NB, 256, 0, stream>>>(cnt, bsum);
    scan_off_kernel<<<1, 256, 0, stream>>>(bsum, NB);
    scan_final_kernel<<<NB, 256, 0, stream>>>(cnt, bsum, row, cursor);
    csr_scatter_kernel<<<(N_EDGES + 255) / 256, 256, 0, stream>>>(srcI, dstI, cursor, srcS, origE);
    selfloop_mean_kernel<<<(N_NODES + 3) / 4, 256, 0, stream>>>(row, origE, ea, flag, lattr);
    se_pass_kernel<<<(N_EDGES + 255) / 256, 256, 0, stream>>>(origE, ea, flag, M1, M2, se1, se2);

    const int GB = (N_NODES + 63) / 64;           // 782 row-blocks

    // ----- layer 1 (H=4, concat) -----
    gemm_mfma_kernel<128, 256, 0><<<GB, 256, 0, stream>>>(x, wf1, xs, flag, N_NODES);
    node_scores_kernel<4><<<(N_NODES + 3) / 4, 256, 0, stream>>>(xs, as1, ad1, flag, sA1, sD1);
    self_pass_kernel<4><<<(N_NODES + 255) / 256, 256, 0, stream>>>(lattr, M1, sA1, sD1, exS);
    agg_fused_kernel<4, 1><<<(N_NODES + 3) / 4, 256, 0, stream>>>(row, srcS, xs, se1, sA1, sD1, exS, b1, flag, h1);

    // ----- layer 2 (H=2, mean) -----
    gemm_mfma_kernel<256, 128, 1><<<GB, 256, 0, stream>>>(h1, wf2, xs, flag, N_NODES);
    node_scores_kernel<2><<<(N_NODES + 3) / 4, 256, 0, stream>>>(xs, as2, ad2, flag, sA2, sD2);
    self_pass_kernel<2><<<(N_NODES + 255) / 256, 256, 0, stream>>>(lattr, M2, sA2, sD2, exS);
    agg_fused_kernel<2, 2><<<(N_NODES + 3) / 4, 256, 0, stream>>>(row, srcS, xs, se2, sA2, sD2, exS, b2, flag, h2);

    // ----- pool + readout -----
    pool_max_kernel<<<N_GRAPHS, 256, 0, stream>>>(h2, batch, gpool);
    readout_kernel<<<N_GRAPHS, 64, 0, stream>>>(gpool, Wr, br, flag, d_out);
}

// Round 7
// 481.081 us; speedup vs baseline: 4.0788x; 1.1233x over previous
//
#include <hip/hip_runtime.h>
#include <hip/hip_bf16.h>

#define DEVINL __device__ __forceinline__
typedef __hip_bfloat16 bf16;

typedef __attribute__((ext_vector_type(8))) __bf16 bf16x8;
typedef __attribute__((ext_vector_type(4))) float f32x4;

static constexpr int N_NODES  = 50000;
static constexpr int N_EDGES  = 800000;
static constexpr int N_GRAPHS = 128;
static constexpr float NEG_SLOPE = 0.2f;

// Dual-path input load: isbf=1 -> storage is bf16, else fp32.
DEVINL float ldIn(const void* __restrict__ p, size_t i, int isbf) {
    if (isbf) return __bfloat162float(((const bf16*)p)[i]);
    return ((const float*)p)[i];
}

DEVINL unsigned short f2bf(float f) {
    bf16 b = __float2bfloat16(f);
    return *reinterpret_cast<unsigned short*>(&b);
}

DEVINL float bfu2f(unsigned short u) {           // bf16 bits -> f32 (shift only)
    return __uint_as_float(((unsigned)u) << 16);
}

template<int H>
DEVINL void ldrow(const unsigned short* __restrict__ p, unsigned short (&v)[H]) {
    if (H == 4) *reinterpret_cast<uint2*>(v)    = *reinterpret_cast<const uint2*>(p);
    else        *reinterpret_cast<unsigned*>(v) = *reinterpret_cast<const unsigned*>(p);
}

DEVINL float lrelu_exp(float sc) {
    sc = sc > 0.f ? sc : NEG_SLOPE * sc;
    return __expf(sc);
}

// ---------- runtime dtype detection (see round-1 notes) ----------
__global__ void detect_dtype_kernel(const unsigned short* __restrict__ xu,
                                    int* __restrict__ flag)
{
    int t = threadIdx.x;
    int bad = 0;
    for (int i = t; i < 1024; i += 64) {
        unsigned u = xu[2 * i];
        float v = __uint_as_float(u << 16);
        if (!(fabsf(v) <= 1e4f)) bad = 1;
    }
    unsigned long long m = __ballot(bad);
    if (t == 0) *flag = m ? 0 : 1;          // 1 = bf16 storage
}

// ---------- tiny setup: M[d][h] = sum_c We[d, h*64+c] * a_e[h, c] ----------
__global__ void build_M_kernel(const void* __restrict__ We1, const void* __restrict__ ae1,
                               const void* __restrict__ We2, const void* __restrict__ ae2,
                               const int* __restrict__ flagp,
                               float* __restrict__ M1, float* __restrict__ M2)
{
    const int isbf = *flagp;
    int t = threadIdx.x;
    if (t < 64) {
        int d = t >> 2, h = t & 3;
        float s = 0.f;
        for (int c = 0; c < 64; ++c)
            s += ldIn(We1, d * 256 + h * 64 + c, isbf) * ldIn(ae1, h * 64 + c, isbf);
        M1[d * 4 + h] = s;
    }
    if (t < 32) {
        int d = t >> 1, h = t & 1;
        float s = 0.f;
        for (int c = 0; c < 64; ++c)
            s += ldIn(We2, d * 128 + h * 64 + c, isbf) * ldIn(ae2, h * 64 + c, isbf);
        M2[d * 2 + h] = s;
    }
}

// ---------- pack W[K,M] into MFMA B-fragment order ----------
template<int K, int M>
__global__ void build_wfrag_kernel(const void* __restrict__ W, const int* __restrict__ flagp,
                                   bf16* __restrict__ Wfrag)
{
    constexpr int KS = K / 32;
    const int isbf = *flagp;
    int idx = blockIdx.x * 256 + threadIdx.x;
    constexpr int total = (M / 16) * KS * 64 * 8;
    if (idx >= total) return;
    int j    = idx & 7;
    int lane = (idx >> 3) & 63;
    int rem  = idx >> 9;
    int ks   = rem % KS;
    int ct   = rem / KS;
    int k = ks * 32 + (lane >> 4) * 8 + j;
    int n = ct * 16 + (lane & 15);
    Wfrag[idx] = __float2bfloat16(ldIn(W, (size_t)k * M + n, isbf));
}

// ---------- MFMA GEMM: C[N,M] = A[N,K] @ W[K,M], C stored bf16 ----------
template<int K, int M, int AMODE>
__global__ __launch_bounds__(256)
void gemm_mfma_kernel(const void* __restrict__ A, const bf16* __restrict__ Wfrag,
                      bf16* __restrict__ C, const int* __restrict__ flagp, int N)
{
    constexpr int KS = K / 32, CT = M / 16;
    constexpr int LDA = K + 8;
    __shared__ __align__(16) unsigned short Asm[64 * LDA];
    const int isbf = *flagp;
    const int tid  = threadIdx.x;
    const int wave = tid >> 6, lane = tid & 63;
    const int n0 = blockIdx.x * 64;

    for (int i = tid; i < 64 * (K / 8); i += 256) {
        int r  = i / (K / 8);
        int kc = (i % (K / 8)) * 8;
        int n  = n0 + r;
        unsigned short v[8] = {0, 0, 0, 0, 0, 0, 0, 0};
        if (n < N) {
            size_t base = (size_t)n * K + kc;
            if (AMODE == 1 || isbf) {
                *reinterpret_cast<uint4*>(v) =
                    *reinterpret_cast<const uint4*>((const unsigned short*)A + base);
            } else {
                const float* Af = (const float*)A + base;
                float4 f0 = *reinterpret_cast<const float4*>(Af);
                float4 f1 = *reinterpret_cast<const float4*>(Af + 4);
                v[0] = f2bf(f0.x); v[1] = f2bf(f0.y); v[2] = f2bf(f0.z); v[3] = f2bf(f0.w);
                v[4] = f2bf(f1.x); v[5] = f2bf(f1.y); v[6] = f2bf(f1.z); v[7] = f2bf(f1.w);
            }
        }
        *reinterpret_cast<uint4*>(&Asm[r * LDA + kc]) = *reinterpret_cast<uint4*>(v);
    }
    __syncthreads();

    f32x4 acc[CT];
    #pragma unroll
    for (int ct = 0; ct < CT; ++ct) acc[ct] = (f32x4){0.f, 0.f, 0.f, 0.f};

    const int arow  = wave * 16 + (lane & 15);
    const int akoff = (lane >> 4) * 8;
    #pragma unroll
    for (int ks = 0; ks < KS; ++ks) {
        bf16x8 af = *reinterpret_cast<const bf16x8*>(&Asm[arow * LDA + ks * 32 + akoff]);
        #pragma unroll
        for (int ct = 0; ct < CT; ++ct) {
            bf16x8 bfr = *reinterpret_cast<const bf16x8*>(
                &Wfrag[(((size_t)ct * KS + ks) * 64 + lane) * 8]);
            acc[ct] = __builtin_amdgcn_mfma_f32_16x16x32_bf16(af, bfr, acc[ct], 0, 0, 0);
        }
    }

    const int crow0 = n0 + wave * 16 + (lane >> 4) * 4;
    const int ccol  = lane & 15;
    #pragma unroll
    for (int ct = 0; ct < CT; ++ct) {
        #pragma unroll
        for (int r = 0; r < 4; ++r) {
            int row = crow0 + r;
            if (row < N) C[(size_t)row * M + ct * 16 + ccol] = __float2bfloat16(acc[ct][r]);
        }
    }
}

// ---------- CSR build ----------
__global__ void csr_count_kernel(const int* __restrict__ dst, int* __restrict__ cnt)
{
    int e = blockIdx.x * blockDim.x + threadIdx.x;
    if (e >= N_EDGES) return;
    atomicAdd(&cnt[dst[e]], 1);
}

// per-256-chunk sums
__global__ __launch_bounds__(256)
void scan_sum_kernel(const int* __restrict__ cnt, int* __restrict__ bsum)
{
    __shared__ int sm[256];
    int i = blockIdx.x * 256 + threadIdx.x;
    sm[threadIdx.x] = (i < N_NODES) ? cnt[i] : 0;
    __syncthreads();
    for (int off = 128; off; off >>= 1) {
        if (threadIdx.x < off) sm[threadIdx.x] += sm[threadIdx.x + off];
        __syncthreads();
    }
    if (threadIdx.x == 0) bsum[blockIdx.x] = sm[0];
}

// single-block exclusive scan of bsum[nb] in place (nb <= 256)
__global__ __launch_bounds__(256)
void scan_off_kernel(int* __restrict__ bsum, int nb)
{
    __shared__ int sm[256];
    int tid = threadIdx.x;
    int v = (tid < nb) ? bsum[tid] : 0;
    sm[tid] = v;
    __syncthreads();
    for (int off = 1; off < 256; off <<= 1) {
        int t = (tid >= off) ? sm[tid - off] : 0;
        __syncthreads();
        sm[tid] += t;
        __syncthreads();
    }
    if (tid < nb) bsum[tid] = sm[tid] - v;
}

__global__ __launch_bounds__(256)
void scan_final_kernel(const int* __restrict__ cnt, const int* __restrict__ bsum,
                       int* __restrict__ row, int* __restrict__ cursor)
{
    __shared__ int sm[256];
    int i = blockIdx.x * 256 + threadIdx.x;
    int tid = threadIdx.x;
    int v = (i < N_NODES) ? cnt[i] : 0;
    sm[tid] = v;
    __syncthreads();
    for (int off = 1; off < 256; off <<= 1) {
        int t = (tid >= off) ? sm[tid - off] : 0;
        __syncthreads();
        sm[tid] += t;
        __syncthreads();
    }
    int excl = sm[tid] - v + bsum[blockIdx.x];
    if (i < N_NODES) { row[i] = excl; cursor[i] = excl; }
    if (i == N_NODES - 1) row[N_NODES] = excl + v;
}

// ---------- scatter + fused edge-attr projection (coalesced ea read!) ----------
// se1[pos][4], se2[pos][2] = attr(e) @ M1, attr(e) @ M2 in CSR slot pos.
__global__ void csr_scatter_kernel(const int* __restrict__ srcI, const int* __restrict__ dstI,
                                   const void* __restrict__ eattr, const int* __restrict__ flagp,
                                   const float* __restrict__ M1, const float* __restrict__ M2,
                                   int* __restrict__ cursor, int* __restrict__ srcS,
                                   float* __restrict__ se1, float* __restrict__ se2)
{
    const int isbf = *flagp;
    int e = blockIdx.x * blockDim.x + threadIdx.x;
    if (e >= N_EDGES) return;
    float attr[16];
    #pragma unroll
    for (int k = 0; k < 16; ++k) attr[k] = ldIn(eattr, (size_t)e * 16 + k, isbf);
    float4 o1 = {0.f, 0.f, 0.f, 0.f};
    float2 o2 = {0.f, 0.f};
    #pragma unroll
    for (int k = 0; k < 16; ++k) {
        o1.x += attr[k] * M1[k * 4 + 0];
        o1.y += attr[k] * M1[k * 4 + 1];
        o1.z += attr[k] * M1[k * 4 + 2];
        o1.w += attr[k] * M1[k * 4 + 3];
        o2.x += attr[k] * M2[k * 2 + 0];
        o2.y += attr[k] * M2[k * 2 + 1];
    }
    int d = dstI[e];
    int pos = atomicAdd(&cursor[d], 1);
    srcS[pos] = srcI[e];
    *reinterpret_cast<float4*>(&se1[(size_t)pos * 4]) = o1;
    *reinterpret_cast<float2*>(&se2[(size_t)pos * 2]) = o2;
}

// ---------- per-node attention logits: one wave per node ----------
template<int H>
__global__ __launch_bounds__(256)
void node_scores_kernel(const bf16* __restrict__ xs, const void* __restrict__ a_src,
                        const void* __restrict__ a_dst, const int* __restrict__ flagp,
                        float* __restrict__ sA, float* __restrict__ sD)
{
    const int isbf = *flagp;
    int wave = (blockIdx.x * 256 + threadIdx.x) >> 6;
    int lane = threadIdx.x & 63;
    if (wave >= N_NODES) return;
    #pragma unroll
    for (int h = 0; h < H; ++h) {
        float v  = __bfloat162float(xs[(size_t)wave * (H * 64) + h * 64 + lane]);
        float ps = v * ldIn(a_src, h * 64 + lane, isbf);
        float pd = v * ldIn(a_dst, h * 64 + lane, isbf);
        for (int off = 32; off; off >>= 1) {
            ps += __shfl_down(ps, off);
            pd += __shfl_down(pd, off);
        }
        if (lane == 0) { sA[wave * H + h] = ps; sD[wave * H + h] = pd; }
    }
}

// ---------- fused score+softmax+aggregate: one wave per dst, lane = chan group ----
// w_j = exp(leaky(sA[s_j] + sD[d] + se[j])); self-loop term from seSum/cnt
// (linearity: M-projection of mean attr == mean of per-edge projections).
// LAYER 1 (H=4): out = relu(agg + b1) -> bf16 h1[N,256]
// LAYER 2 (H=2): out = mean_heads(agg) + b2 -> fp32 h2[N,64]
template<int H, int LAYER>
__global__ __launch_bounds__(256)
void agg_fused_kernel(const int* __restrict__ row, const int* __restrict__ srcS,
                      const bf16* __restrict__ xs, const float* __restrict__ seE,
                      const float* __restrict__ sA, const float* __restrict__ sD,
                      const void* __restrict__ bias,
                      const int* __restrict__ flagp, void* __restrict__ out)
{
    const int isbf = *flagp;
    int dv = (blockIdx.x * 256 + threadIdx.x) >> 6;
    const int d = __builtin_amdgcn_readfirstlane(dv);   // wave-uniform -> scalar loads
    const int lane = threadIdx.x & 63;
    if (d >= N_NODES) return;
    const int h = (lane * H) >> 6;                      // this lane's head
    const unsigned short* xsu = (const unsigned short*)xs;
    const float sDv = sD[(size_t)d * H + h];
    const float sAd = sA[(size_t)d * H + h];

    float acc[H];
    #pragma unroll
    for (int i = 0; i < H; ++i) acc[i] = 0.f;
    float den = 0.f, seSum = 0.f;

    const int b = row[d], eend = row[d + 1];
    int j = b;
    for (; j + 7 < eend; j += 8) {
        int s[8];
        float se[8], sa[8];
        unsigned short v[8][H];
        #pragma unroll
        for (int u = 0; u < 8; ++u) s[u] = srcS[j + u];
        #pragma unroll
        for (int u = 0; u < 8; ++u) se[u] = seE[(size_t)(j + u) * H + h];
        #pragma unroll
        for (int u = 0; u < 8; ++u) sa[u] = sA[(size_t)s[u] * H + h];
        #pragma unroll
        for (int u = 0; u < 8; ++u) ldrow<H>(&xsu[(size_t)s[u] * (H * 64) + lane * H], v[u]);
        #pragma unroll
        for (int u = 0; u < 8; ++u) {
            float w = lrelu_exp(sa[u] + sDv + se[u]);
            seSum += se[u];
            den += w;
            #pragma unroll
            for (int i = 0; i < H; ++i) acc[i] += w * bfu2f(v[u][i]);
        }
    }
    for (; j < eend; ++j) {
        const int s = srcS[j];
        const float se = seE[(size_t)j * H + h];
        const float sa = sA[(size_t)s * H + h];
        unsigned short v[H];
        ldrow<H>(&xsu[(size_t)s * (H * 64) + lane * H], v);
        const float w = lrelu_exp(sa + sDv + se);
        seSum += se;
        den += w;
        #pragma unroll
        for (int i = 0; i < H; ++i) acc[i] += w * bfu2f(v[i]);
    }

    // self loop: attr = mean of incident edge attrs -> se_self = seSum/cnt
    {
        const int cntv = eend - b;
        const float seM = seSum / fmaxf((float)cntv, 1.f);
        const float wS = lrelu_exp(sAd + sDv + seM);
        unsigned short v[H];
        ldrow<H>(&xsu[(size_t)d * (H * 64) + lane * H], v);
        den += wS;
        #pragma unroll
        for (int i = 0; i < H; ++i) acc[i] += wS * bfu2f(v[i]);
    }

    const float rden = 1.f / (den + 1e-16f);
    if (LAYER == 1) {
        unsigned short o[H];
        #pragma unroll
        for (int i = 0; i < H; ++i) {
            float v = acc[i] * rden + ldIn(bias, lane * H + i, isbf);
            o[i] = f2bf(v > 0.f ? v : 0.f);
        }
        *reinterpret_cast<uint2*>(&((unsigned short*)out)[(size_t)d * (H * 64) + lane * H]) =
            *reinterpret_cast<uint2*>(o);
    } else {
        // lane (<32): channels {2*lane, 2*lane+1} head0; lane+32 same channels head1
        float v0 = acc[0] * rden, v1 = acc[1] * rden;
        float p0 = __shfl(v0, lane + 32), p1 = __shfl(v1, lane + 32);
        if (lane < 32) {
            float2 o;
            o.x = 0.5f * (v0 + p0) + ldIn(bias, lane * 2 + 0, isbf);
            o.y = 0.5f * (v1 + p1) + ldIn(bias, lane * 2 + 1, isbf);
            *reinterpret_cast<float2*>(&((float*)out)[(size_t)d * 64 + lane * 2]) = o;
        }
    }
}

// ---------- pooling ----------
__global__ __launch_bounds__(256)
void pool_max_kernel(const float* __restrict__ h2, const int* __restrict__ batch,
                     float* __restrict__ g)
{
    int gi = blockIdx.x;
    int lo = 0, hi = N_NODES;
    while (lo < hi) { int mid = (lo + hi) >> 1; if (batch[mid] < gi) lo = mid + 1; else hi = mid; }
    int start = lo;
    lo = start; hi = N_NODES;
    while (lo < hi) { int mid = (lo + hi) >> 1; if (batch[mid] < gi + 1) lo = mid + 1; else hi = mid; }
    int end = lo;
    int c = threadIdx.x & 63, chunk = threadIdx.x >> 6;
    float m = -INFINITY;
    for (int n = start + chunk; n < end; n += 4) m = fmaxf(m, h2[(size_t)n * 64 + c]);
    __shared__ float sm[256];
    sm[threadIdx.x] = m;
    __syncthreads();
    if (threadIdx.x < 64) {
        m = fmaxf(fmaxf(sm[threadIdx.x], sm[threadIdx.x + 64]),
                  fmaxf(sm[threadIdx.x + 128], sm[threadIdx.x + 192]));
        g[gi * 64 + threadIdx.x] = m;
    }
}

// ---------- readout ----------
__global__ void readout_kernel(const float* __restrict__ g, const void* __restrict__ Wr,
                               const void* __restrict__ br, const int* __restrict__ flagp,
                               void* __restrict__ out)
{
    const int isbf = *flagp;
    int gi = blockIdx.x;
    int lane = threadIdx.x;
    float p = g[gi * 64 + lane] * ldIn(Wr, lane, isbf);
    for (int off = 32; off; off >>= 1) p += __shfl_down(p, off);
    if (lane == 0) {
        float r = p + ldIn(br, 0, isbf);
        if (isbf) ((bf16*)out)[gi] = __float2bfloat16(r);
        else      ((float*)out)[gi] = r;
    }
}

extern "C" void kernel_launch(void* const* d_in, const int* in_sizes, int n_in,
                              void* d_out, int out_size, void* d_ws, size_t ws_size,
                              hipStream_t stream)
{
    const void* x     = d_in[0];
    const void* ea    = d_in[1];
    const int*  eidx  = (const int*)d_in[2];
    const int*  batch = (const int*)d_in[3];
    const void* W1  = d_in[4];
    const void* as1 = d_in[5];
    const void* ad1 = d_in[6];
    const void* We1 = d_in[7];
    const void* ae1 = d_in[8];
    const void* b1  = d_in[9];
    const void* W2  = d_in[10];
    const void* as2 = d_in[11];
    const void* ad2 = d_in[12];
    const void* We2 = d_in[13];
    const void* ae2 = d_in[14];
    const void* b2  = d_in[15];
    const void* Wr  = d_in[16];
    const void* br  = d_in[17];

    const int* srcI = eidx;
    const int* dstI = eidx + N_EDGES;

    // ---- workspace layout (float-index offsets), peak ~77 MB ----
    float* ws    = (float*)d_ws;
    bf16*  xs    = (bf16*)ws;                     // [0, 6.4M): N*256 bf16 (L2: N*128)
    bf16*  h1    = (bf16*)(ws + 6400000);         // N*256 bf16 -> [6.4M, 12.8M)
    float* h2    = ws + 6400000;                  // N*64 fp32 overlay (h1 dead after gemm2)
    float* se1   = ws + 12800000;                 // E*4 -> [12.8M, 16M)
    float* se2   = ws + 16000000;                 // E*2 -> [16M, 17.6M)
    float* sA1   = ws + 17600000;                 // N*4
    float* sD1   = ws + 17800000;                 // N*4
    float* sA2   = ws + 18000000;                 // N*2
    float* sD2   = ws + 18100000;                 // N*2
    int*   ib    = (int*)(ws + 18200000);
    int*   row    = ib;                           // N+1
    int*   cursor = ib + 50016;                   // N
    int*   cnt    = ib + 100032;                  // N
    int*   bsum   = ib + 150048;                  // 256 (pad to 352)
    int*   srcS   = ib + 150400;                  // E
    float* misc  = ws + 18200000 + 950400;
    int*   flag  = (int*)misc;                    // 1
    float* M1    = misc + 16;                     // 64
    float* M2    = misc + 80;                     // 32
    float* gpool = misc + 112;                    // 128*64
    bf16*  wf1   = (bf16*)(misc + 8320);          // 32768 bf16
    bf16*  wf2   = (bf16*)(misc + 8320 + 16384);  // 32768 bf16

    hipMemsetAsync(cnt, 0, N_NODES * sizeof(int), stream);

    detect_dtype_kernel<<<1, 64, 0, stream>>>((const unsigned short*)x, flag);
    build_M_kernel<<<1, 64, 0, stream>>>(We1, ae1, We2, ae2, flag, M1, M2);
    build_wfrag_kernel<128, 256><<<128, 256, 0, stream>>>(W1, flag, wf1);
    build_wfrag_kernel<256, 128><<<128, 256, 0, stream>>>(W2, flag, wf2);

    // ----- CSR over dst (parallel scan) + fused se projection -----
    const int NB = (N_NODES + 255) / 256;         // 196
    csr_count_kernel<<<(N_EDGES + 255) / 256, 256, 0, stream>>>(dstI, cnt);
    scan_sum_kernel<<<NB, 256, 0, stream>>>(cnt, bsum);
    scan_off_kernel<<<1, 256, 0, stream>>>(bsum, NB);
    scan_final_kernel<<<NB, 256, 0, stream>>>(cnt, bsum, row, cursor);
    csr_scatter_kernel<<<(N_EDGES + 255) / 256, 256, 0, stream>>>(
        srcI, dstI, ea, flag, M1, M2, cursor, srcS, se1, se2);

    const int GB = (N_NODES + 63) / 64;           // 782 row-blocks

    // ----- layer 1 (H=4, concat) -----
    gemm_mfma_kernel<128, 256, 0><<<GB, 256, 0, stream>>>(x, wf1, xs, flag, N_NODES);
    node_scores_kernel<4><<<(N_NODES + 3) / 4, 256, 0, stream>>>(xs, as1, ad1, flag, sA1, sD1);
    agg_fused_kernel<4, 1><<<(N_NODES + 3) / 4, 256, 0, stream>>>(
        row, srcS, xs, se1, sA1, sD1, b1, flag, h1);

    // ----- layer 2 (H=2, mean) -----
    gemm_mfma_kernel<256, 128, 1><<<GB, 256, 0, stream>>>(h1, wf2, xs, flag, N_NODES);
    node_scores_kernel<2><<<(N_NODES + 3) / 4, 256, 0, stream>>>(xs, as2, ad2, flag, sA2, sD2);
    agg_fused_kernel<2, 2><<<(N_NODES + 3) / 4, 256, 0, stream>>>(
        row, srcS, xs, se2, sA2, sD2, b2, flag, h2);

    // ----- pool + readout -----
    pool_max_kernel<<<N_GRAPHS, 256, 0, stream>>>(h2, batch, gpool);
    readout_kernel<<<N_GRAPHS, 64, 0, stream>>>(gpool, Wr, br, flag, d_out);
}

// Round 8
// 429.892 us; speedup vs baseline: 4.5645x; 1.1191x over previous
//
#include <hip/hip_runtime.h>
#include <hip/hip_bf16.h>
#include <hip/hip_fp16.h>

#define DEVINL __device__ __forceinline__
typedef __hip_bfloat16 bf16;

typedef __attribute__((ext_vector_type(8))) __bf16 bf16x8;
typedef __attribute__((ext_vector_type(4))) float f32x4;

static constexpr int N_NODES  = 50000;
static constexpr int N_EDGES  = 800000;
static constexpr int N_GRAPHS = 128;
static constexpr float NEG_SLOPE = 0.2f;

// Dual-path input load: isbf=1 -> storage is bf16, else fp32.
DEVINL float ldIn(const void* __restrict__ p, size_t i, int isbf) {
    if (isbf) return __bfloat162float(((const bf16*)p)[i]);
    return ((const float*)p)[i];
}

DEVINL unsigned short f2bf(float f) {
    bf16 b = __float2bfloat16(f);
    return *reinterpret_cast<unsigned short*>(&b);
}

DEVINL float bfu2f(unsigned short u) {           // bf16 bits -> f32 (shift only)
    return __uint_as_float(((unsigned)u) << 16);
}

DEVINL unsigned f2hbits(float f) {
    __half h = __float2half(f);
    return (unsigned)*reinterpret_cast<unsigned short*>(&h);
}

DEVINL float hbits2f(unsigned bits) {
    unsigned short us = (unsigned short)bits;
    __half h = *reinterpret_cast<__half*>(&us);
    return __half2float(h);
}

template<int H>
DEVINL void ldrow(const unsigned short* __restrict__ p, unsigned short (&v)[H]) {
    if (H == 4) *reinterpret_cast<uint2*>(v)    = *reinterpret_cast<const uint2*>(p);
    else        *reinterpret_cast<unsigned*>(v) = *reinterpret_cast<const unsigned*>(p);
}

DEVINL float lrelu_exp(float sc) {
    sc = sc > 0.f ? sc : NEG_SLOPE * sc;
    return __expf(sc);
}

// ---------- runtime dtype detection (see round-1 notes) ----------
__global__ void detect_dtype_kernel(const unsigned short* __restrict__ xu,
                                    int* __restrict__ flag)
{
    int t = threadIdx.x;
    int bad = 0;
    for (int i = t; i < 1024; i += 64) {
        unsigned u = xu[2 * i];
        float v = __uint_as_float(u << 16);
        if (!(fabsf(v) <= 1e4f)) bad = 1;
    }
    unsigned long long m = __ballot(bad);
    if (t == 0) *flag = m ? 0 : 1;          // 1 = bf16 storage
}

// ---------- tiny setup: M[d][h] = sum_c We[d, h*64+c] * a_e[h, c] ----------
__global__ void build_M_kernel(const void* __restrict__ We1, const void* __restrict__ ae1,
                               const void* __restrict__ We2, const void* __restrict__ ae2,
                               const int* __restrict__ flagp,
                               float* __restrict__ M1, float* __restrict__ M2)
{
    const int isbf = *flagp;
    int t = threadIdx.x;
    if (t < 64) {
        int d = t >> 2, h = t & 3;
        float s = 0.f;
        for (int c = 0; c < 64; ++c)
            s += ldIn(We1, d * 256 + h * 64 + c, isbf) * ldIn(ae1, h * 64 + c, isbf);
        M1[d * 4 + h] = s;
    }
    if (t < 32) {
        int d = t >> 1, h = t & 1;
        float s = 0.f;
        for (int c = 0; c < 64; ++c)
            s += ldIn(We2, d * 128 + h * 64 + c, isbf) * ldIn(ae2, h * 64 + c, isbf);
        M2[d * 2 + h] = s;
    }
}

// ---------- pack W[K,M] into MFMA B-fragment order ----------
template<int K, int M>
__global__ void build_wfrag_kernel(const void* __restrict__ W, const int* __restrict__ flagp,
                                   bf16* __restrict__ Wfrag)
{
    constexpr int KS = K / 32;
    const int isbf = *flagp;
    int idx = blockIdx.x * 256 + threadIdx.x;
    constexpr int total = (M / 16) * KS * 64 * 8;
    if (idx >= total) return;
    int j    = idx & 7;
    int lane = (idx >> 3) & 63;
    int rem  = idx >> 9;
    int ks   = rem % KS;
    int ct   = rem / KS;
    int k = ks * 32 + (lane >> 4) * 8 + j;
    int n = ct * 16 + (lane & 15);
    Wfrag[idx] = __float2bfloat16(ldIn(W, (size_t)k * M + n, isbf));
}

// ---------- MFMA GEMM + fused node-score epilogue ----------
// C[N,M] = A[N,K] @ W[K,M] (bf16 out); also sA[n][h] = dot(C-row head h, a_src),
// sD likewise. h = ct>>2 for both layer shapes (64 channels/head, 16 per ct).
template<int K, int M, int AMODE, int H>
__global__ __launch_bounds__(256)
void gemm_mfma_kernel(const void* __restrict__ A, const bf16* __restrict__ Wfrag,
                      bf16* __restrict__ C, const int* __restrict__ flagp, int N,
                      const void* __restrict__ a_src, const void* __restrict__ a_dst,
                      float* __restrict__ sA, float* __restrict__ sD)
{
    constexpr int KS = K / 32, CT = M / 16;
    constexpr int LDA = K + 8;
    __shared__ __align__(16) unsigned short Asm[64 * LDA];
    const int isbf = *flagp;
    const int tid  = threadIdx.x;
    const int wave = tid >> 6, lane = tid & 63;
    const int n0 = blockIdx.x * 64;

    for (int i = tid; i < 64 * (K / 8); i += 256) {
        int r  = i / (K / 8);
        int kc = (i % (K / 8)) * 8;
        int n  = n0 + r;
        unsigned short v[8] = {0, 0, 0, 0, 0, 0, 0, 0};
        if (n < N) {
            size_t base = (size_t)n * K + kc;
            if (AMODE == 1 || isbf) {
                *reinterpret_cast<uint4*>(v) =
                    *reinterpret_cast<const uint4*>((const unsigned short*)A + base);
            } else {
                const float* Af = (const float*)A + base;
                float4 f0 = *reinterpret_cast<const float4*>(Af);
                float4 f1 = *reinterpret_cast<const float4*>(Af + 4);
                v[0] = f2bf(f0.x); v[1] = f2bf(f0.y); v[2] = f2bf(f0.z); v[3] = f2bf(f0.w);
                v[4] = f2bf(f1.x); v[5] = f2bf(f1.y); v[6] = f2bf(f1.z); v[7] = f2bf(f1.w);
            }
        }
        *reinterpret_cast<uint4*>(&Asm[r * LDA + kc]) = *reinterpret_cast<uint4*>(v);
    }
    __syncthreads();

    f32x4 acc[CT];
    #pragma unroll
    for (int ct = 0; ct < CT; ++ct) acc[ct] = (f32x4){0.f, 0.f, 0.f, 0.f};

    const int arow  = wave * 16 + (lane & 15);
    const int akoff = (lane >> 4) * 8;
    #pragma unroll
    for (int ks = 0; ks < KS; ++ks) {
        bf16x8 af = *reinterpret_cast<const bf16x8*>(&Asm[arow * LDA + ks * 32 + akoff]);
        #pragma unroll
        for (int ct = 0; ct < CT; ++ct) {
            bf16x8 bfr = *reinterpret_cast<const bf16x8*>(
                &Wfrag[(((size_t)ct * KS + ks) * 64 + lane) * 8]);
            acc[ct] = __builtin_amdgcn_mfma_f32_16x16x32_bf16(af, bfr, acc[ct], 0, 0, 0);
        }
    }

    // ---- store C: row = (lane>>4)*4 + reg, col = lane&15 (verified layout) ----
    const int crow0 = n0 + wave * 16 + (lane >> 4) * 4;
    const int ccol  = lane & 15;
    #pragma unroll
    for (int ct = 0; ct < CT; ++ct) {
        #pragma unroll
        for (int r = 0; r < 4; ++r) {
            int row = crow0 + r;
            if (row < N) C[(size_t)row * M + ct * 16 + ccol] = __float2bfloat16(acc[ct][r]);
        }
    }

    // ---- fused attention logits ----
    float psA[4][H], psD[4][H];
    #pragma unroll
    for (int r = 0; r < 4; ++r)
        #pragma unroll
        for (int hh = 0; hh < H; ++hh) { psA[r][hh] = 0.f; psD[r][hh] = 0.f; }
    #pragma unroll
    for (int ct = 0; ct < CT; ++ct) {
        float as = ldIn(a_src, ct * 16 + ccol, isbf);
        float ad = ldIn(a_dst, ct * 16 + ccol, isbf);
        const int hh = ct >> 2;
        #pragma unroll
        for (int r = 0; r < 4; ++r) {
            psA[r][hh] += acc[ct][r] * as;
            psD[r][hh] += acc[ct][r] * ad;
        }
    }
    #pragma unroll
    for (int m = 1; m < 16; m <<= 1) {
        #pragma unroll
        for (int r = 0; r < 4; ++r)
            #pragma unroll
            for (int hh = 0; hh < H; ++hh) {
                psA[r][hh] += __shfl_xor(psA[r][hh], m);
                psD[r][hh] += __shfl_xor(psD[r][hh], m);
            }
    }
    if (ccol == 0) {
        #pragma unroll
        for (int r = 0; r < 4; ++r) {
            int row = crow0 + r;
            if (row < N) {
                #pragma unroll
                for (int hh = 0; hh < H; ++hh) {
                    sA[(size_t)row * H + hh] = psA[r][hh];
                    sD[(size_t)row * H + hh] = psD[r][hh];
                }
            }
        }
    }
}

// ---------- CSR build ----------
__global__ void csr_count_kernel(const int* __restrict__ dst, int* __restrict__ cnt)
{
    int e = blockIdx.x * blockDim.x + threadIdx.x;
    if (e >= N_EDGES) return;
    atomicAdd(&cnt[dst[e]], 1);
}

__global__ __launch_bounds__(256)
void scan_sum_kernel(const int* __restrict__ cnt, int* __restrict__ bsum)
{
    __shared__ int sm[256];
    int i = blockIdx.x * 256 + threadIdx.x;
    sm[threadIdx.x] = (i < N_NODES) ? cnt[i] : 0;
    __syncthreads();
    for (int off = 128; off; off >>= 1) {
        if (threadIdx.x < off) sm[threadIdx.x] += sm[threadIdx.x + off];
        __syncthreads();
    }
    if (threadIdx.x == 0) bsum[blockIdx.x] = sm[0];
}

__global__ __launch_bounds__(256)
void scan_off_kernel(int* __restrict__ bsum, int nb)
{
    __shared__ int sm[256];
    int tid = threadIdx.x;
    int v = (tid < nb) ? bsum[tid] : 0;
    sm[tid] = v;
    __syncthreads();
    for (int off = 1; off < 256; off <<= 1) {
        int t = (tid >= off) ? sm[tid - off] : 0;
        __syncthreads();
        sm[tid] += t;
        __syncthreads();
    }
    if (tid < nb) bsum[tid] = sm[tid] - v;
}

__global__ __launch_bounds__(256)
void scan_final_kernel(const int* __restrict__ cnt, const int* __restrict__ bsum,
                       int* __restrict__ row, int* __restrict__ cursor)
{
    __shared__ int sm[256];
    int i = blockIdx.x * 256 + threadIdx.x;
    int tid = threadIdx.x;
    int v = (i < N_NODES) ? cnt[i] : 0;
    sm[tid] = v;
    __syncthreads();
    for (int off = 1; off < 256; off <<= 1) {
        int t = (tid >= off) ? sm[tid - off] : 0;
        __syncthreads();
        sm[tid] += t;
        __syncthreads();
    }
    int excl = sm[tid] - v + bsum[blockIdx.x];
    if (i < N_NODES) { row[i] = excl; cursor[i] = excl; }
    if (i == N_NODES - 1) row[N_NODES] = excl + v;
}

// ---------- scatter: ONE packed 16-B record per edge ----------
// rec = { src:int, se1:4xfp16, se2:2xfp16 }; se = attr(e) @ M (coalesced ea read).
__global__ void csr_scatter_kernel(const int* __restrict__ srcI, const int* __restrict__ dstI,
                                   const void* __restrict__ eattr, const int* __restrict__ flagp,
                                   const float* __restrict__ M1, const float* __restrict__ M2,
                                   int* __restrict__ cursor, uint4* __restrict__ erec)
{
    const int isbf = *flagp;
    int e = blockIdx.x * blockDim.x + threadIdx.x;
    if (e >= N_EDGES) return;
    float attr[16];
    #pragma unroll
    for (int k = 0; k < 16; ++k) attr[k] = ldIn(eattr, (size_t)e * 16 + k, isbf);
    float4 o1 = {0.f, 0.f, 0.f, 0.f};
    float2 o2 = {0.f, 0.f};
    #pragma unroll
    for (int k = 0; k < 16; ++k) {
        o1.x += attr[k] * M1[k * 4 + 0];
        o1.y += attr[k] * M1[k * 4 + 1];
        o1.z += attr[k] * M1[k * 4 + 2];
        o1.w += attr[k] * M1[k * 4 + 3];
        o2.x += attr[k] * M2[k * 2 + 0];
        o2.y += attr[k] * M2[k * 2 + 1];
    }
    int d = dstI[e];
    int pos = atomicAdd(&cursor[d], 1);
    uint4 rec;
    rec.x = (unsigned)srcI[e];
    rec.y = f2hbits(o1.x) | (f2hbits(o1.y) << 16);
    rec.z = f2hbits(o1.z) | (f2hbits(o1.w) << 16);
    rec.w = f2hbits(o2.x) | (f2hbits(o2.y) << 16);
    erec[pos] = rec;
}

// ---------- fused score+softmax+aggregate: one wave per dst, lane = chan group ----
// w_j = exp(leaky(sA[s_j] + sD[d] + se[j])); self-loop from seSum/cnt (linearity).
// LAYER 1 (H=4): out = relu(agg + b1) -> bf16 h1[N,256]
// LAYER 2 (H=2): out = mean_heads(agg) + b2 -> fp32 h2[N,64]
template<int H, int LAYER>
__global__ __launch_bounds__(256)
void agg_fused_kernel(const int* __restrict__ row, const uint4* __restrict__ erec,
                      const bf16* __restrict__ xs,
                      const float* __restrict__ sA, const float* __restrict__ sD,
                      const void* __restrict__ bias,
                      const int* __restrict__ flagp, void* __restrict__ out)
{
    const int isbf = *flagp;
    int dv = (blockIdx.x * 256 + threadIdx.x) >> 6;
    const int d = __builtin_amdgcn_readfirstlane(dv);   // wave-uniform -> scalar loads
    const int lane = threadIdx.x & 63;
    if (d >= N_NODES) return;
    const int h = (lane * H) >> 6;                      // this lane's head
    const unsigned short* xsu = (const unsigned short*)xs;
    const float sDv = sD[(size_t)d * H + h];
    const float sAd = sA[(size_t)d * H + h];

    float acc[H];
    #pragma unroll
    for (int i = 0; i < H; ++i) acc[i] = 0.f;
    float den = 0.f, seSum = 0.f;

    const int b = row[d], eend = row[d + 1];
    int j = b;
    for (; j + 7 < eend; j += 8) {
        int s[8];
        float se[8], sa[8];
        unsigned short v[8][H];
        #pragma unroll
        for (int u = 0; u < 8; ++u) {
            uint4 rv = erec[j + u];
            s[u] = (int)rv.x;
            if (H == 4) {
                unsigned w16 = (h & 2) ? rv.z : rv.y;
                se[u] = hbits2f((h & 1) ? (w16 >> 16) : (w16 & 0xffffu));
            } else {
                se[u] = hbits2f(h ? (rv.w >> 16) : (rv.w & 0xffffu));
            }
        }
        #pragma unroll
        for (int u = 0; u < 8; ++u) sa[u] = sA[(size_t)s[u] * H + h];
        #pragma unroll
        for (int u = 0; u < 8; ++u) ldrow<H>(&xsu[(size_t)s[u] * (H * 64) + lane * H], v[u]);
        #pragma unroll
        for (int u = 0; u < 8; ++u) {
            float w = lrelu_exp(sa[u] + sDv + se[u]);
            seSum += se[u];
            den += w;
            #pragma unroll
            for (int i = 0; i < H; ++i) acc[i] += w * bfu2f(v[u][i]);
        }
    }
    for (; j < eend; ++j) {
        uint4 rv = erec[j];
        const int s = (int)rv.x;
        float se;
        if (H == 4) {
            unsigned w16 = (h & 2) ? rv.z : rv.y;
            se = hbits2f((h & 1) ? (w16 >> 16) : (w16 & 0xffffu));
        } else {
            se = hbits2f(h ? (rv.w >> 16) : (rv.w & 0xffffu));
        }
        const float sa = sA[(size_t)s * H + h];
        unsigned short v[H];
        ldrow<H>(&xsu[(size_t)s * (H * 64) + lane * H], v);
        const float w = lrelu_exp(sa + sDv + se);
        seSum += se;
        den += w;
        #pragma unroll
        for (int i = 0; i < H; ++i) acc[i] += w * bfu2f(v[i]);
    }

    // self loop: attr = mean of incident edge attrs -> se_self = seSum/cnt
    {
        const int cntv = eend - b;
        const float seM = seSum / fmaxf((float)cntv, 1.f);
        const float wS = lrelu_exp(sAd + sDv + seM);
        unsigned short v[H];
        ldrow<H>(&xsu[(size_t)d * (H * 64) + lane * H], v);
        den += wS;
        #pragma unroll
        for (int i = 0; i < H; ++i) acc[i] += wS * bfu2f(v[i]);
    }

    const float rden = 1.f / (den + 1e-16f);
    if (LAYER == 1) {
        unsigned short o[H];
        #pragma unroll
        for (int i = 0; i < H; ++i) {
            float v = acc[i] * rden + ldIn(bias, lane * H + i, isbf);
            o[i] = f2bf(v > 0.f ? v : 0.f);
        }
        *reinterpret_cast<uint2*>(&((unsigned short*)out)[(size_t)d * (H * 64) + lane * H]) =
            *reinterpret_cast<uint2*>(o);
    } else {
        // lane (<32): channels {2*lane, 2*lane+1} head0; lane+32 same channels head1
        float v0 = acc[0] * rden, v1 = acc[1] * rden;
        float p0 = __shfl(v0, lane + 32), p1 = __shfl(v1, lane + 32);
        if (lane < 32) {
            float2 o;
            o.x = 0.5f * (v0 + p0) + ldIn(bias, lane * 2 + 0, isbf);
            o.y = 0.5f * (v1 + p1) + ldIn(bias, lane * 2 + 1, isbf);
            *reinterpret_cast<float2*>(&((float*)out)[(size_t)d * 64 + lane * 2]) = o;
        }
    }
}

// ---------- pooling ----------
__global__ __launch_bounds__(256)
void pool_max_kernel(const float* __restrict__ h2, const int* __restrict__ batch,
                     float* __restrict__ g)
{
    int gi = blockIdx.x;
    int lo = 0, hi = N_NODES;
    while (lo < hi) { int mid = (lo + hi) >> 1; if (batch[mid] < gi) lo = mid + 1; else hi = mid; }
    int start = lo;
    lo = start; hi = N_NODES;
    while (lo < hi) { int mid = (lo + hi) >> 1; if (batch[mid] < gi + 1) lo = mid + 1; else hi = mid; }
    int end = lo;
    int c = threadIdx.x & 63, chunk = threadIdx.x >> 6;
    float m = -INFINITY;
    for (int n = start + chunk; n < end; n += 4) m = fmaxf(m, h2[(size_t)n * 64 + c]);
    __shared__ float sm[256];
    sm[threadIdx.x] = m;
    __syncthreads();
    if (threadIdx.x < 64) {
        m = fmaxf(fmaxf(sm[threadIdx.x], sm[threadIdx.x + 64]),
                  fmaxf(sm[threadIdx.x + 128], sm[threadIdx.x + 192]));
        g[gi * 64 + threadIdx.x] = m;
    }
}

// ---------- readout ----------
__global__ void readout_kernel(const float* __restrict__ g, const void* __restrict__ Wr,
                               const void* __restrict__ br, const int* __restrict__ flagp,
                               void* __restrict__ out)
{
    const int isbf = *flagp;
    int gi = blockIdx.x;
    int lane = threadIdx.x;
    float p = g[gi * 64 + lane] * ldIn(Wr, lane, isbf);
    for (int off = 32; off; off >>= 1) p += __shfl_down(p, off);
    if (lane == 0) {
        float r = p + ldIn(br, 0, isbf);
        if (isbf) ((bf16*)out)[gi] = __float2bfloat16(r);
        else      ((float*)out)[gi] = r;
    }
}

extern "C" void kernel_launch(void* const* d_in, const int* in_sizes, int n_in,
                              void* d_out, int out_size, void* d_ws, size_t ws_size,
                              hipStream_t stream)
{
    const void* x     = d_in[0];
    const void* ea    = d_in[1];
    const int*  eidx  = (const int*)d_in[2];
    const int*  batch = (const int*)d_in[3];
    const void* W1  = d_in[4];
    const void* as1 = d_in[5];
    const void* ad1 = d_in[6];
    const void* We1 = d_in[7];
    const void* ae1 = d_in[8];
    const void* b1  = d_in[9];
    const void* W2  = d_in[10];
    const void* as2 = d_in[11];
    const void* ad2 = d_in[12];
    const void* We2 = d_in[13];
    const void* ae2 = d_in[14];
    const void* b2  = d_in[15];
    const void* Wr  = d_in[16];
    const void* br  = d_in[17];

    const int* srcI = eidx;
    const int* dstI = eidx + N_EDGES;

    // ---- workspace layout (float-index offsets), peak ~68 MB ----
    float* ws    = (float*)d_ws;
    bf16*  xs    = (bf16*)ws;                     // [0, 6.4M): N*256 bf16 (L2: N*128)
    bf16*  h1    = (bf16*)(ws + 6400000);         // N*256 bf16 -> [6.4M, 12.8M)
    float* h2    = ws + 6400000;                  // N*64 fp32 overlay (h1 dead after gemm2)
    uint4* erec  = (uint4*)(ws + 12800000);       // E 16-B records -> [12.8M, 16M)
    float* sA1   = ws + 16000000;                 // N*4
    float* sD1   = ws + 16200000;                 // N*4
    float* sA2   = ws + 16400000;                 // N*2
    float* sD2   = ws + 16500000;                 // N*2
    int*   ib    = (int*)(ws + 16600000);
    int*   row    = ib;                           // N+1
    int*   cursor = ib + 50016;                   // N
    int*   cnt    = ib + 100032;                  // N
    int*   bsum   = ib + 150048;                  // 256 (pad to 352)
    float* misc  = ws + 16600000 + 150400;
    int*   flag  = (int*)misc;                    // 1
    float* M1    = misc + 16;                     // 64
    float* M2    = misc + 80;                     // 32
    float* gpool = misc + 112;                    // 128*64
    bf16*  wf1   = (bf16*)(misc + 8320);          // 32768 bf16
    bf16*  wf2   = (bf16*)(misc + 8320 + 16384);  // 32768 bf16

    hipMemsetAsync(cnt, 0, N_NODES * sizeof(int), stream);

    detect_dtype_kernel<<<1, 64, 0, stream>>>((const unsigned short*)x, flag);
    build_M_kernel<<<1, 64, 0, stream>>>(We1, ae1, We2, ae2, flag, M1, M2);
    build_wfrag_kernel<128, 256><<<128, 256, 0, stream>>>(W1, flag, wf1);
    build_wfrag_kernel<256, 128><<<128, 256, 0, stream>>>(W2, flag, wf2);

    // ----- CSR over dst (parallel scan) + fused se projection, packed records -----
    const int NB = (N_NODES + 255) / 256;         // 196
    csr_count_kernel<<<(N_EDGES + 255) / 256, 256, 0, stream>>>(dstI, cnt);
    scan_sum_kernel<<<NB, 256, 0, stream>>>(cnt, bsum);
    scan_off_kernel<<<1, 256, 0, stream>>>(bsum, NB);
    scan_final_kernel<<<NB, 256, 0, stream>>>(cnt, bsum, row, cursor);
    csr_scatter_kernel<<<(N_EDGES + 255) / 256, 256, 0, stream>>>(
        srcI, dstI, ea, flag, M1, M2, cursor, erec);

    const int GB = (N_NODES + 63) / 64;           // 782 row-blocks

    // ----- layer 1 (H=4, concat); node scores fused into GEMM epilogue -----
    gemm_mfma_kernel<128, 256, 0, 4><<<GB, 256, 0, stream>>>(
        x, wf1, xs, flag, N_NODES, as1, ad1, sA1, sD1);
    agg_fused_kernel<4, 1><<<(N_NODES + 3) / 4, 256, 0, stream>>>(
        row, erec, xs, sA1, sD1, b1, flag, h1);

    // ----- layer 2 (H=2, mean) -----
    gemm_mfma_kernel<256, 128, 1, 2><<<GB, 256, 0, stream>>>(
        h1, wf2, xs, flag, N_NODES, as2, ad2, sA2, sD2);
    agg_fused_kernel<2, 2><<<(N_NODES + 3) / 4, 256, 0, stream>>>(
        row, erec, xs, sA2, sD2, b2, flag, h2);

    // ----- pool + readout -----
    pool_max_kernel<<<N_GRAPHS, 256, 0, stream>>>(h2, batch, gpool);
    readout_kernel<<<N_GRAPHS, 64, 0, stream>>>(gpool, Wr, br, flag, d_out);
}

// Round 9
// 423.700 us; speedup vs baseline: 4.6312x; 1.0146x over previous
//
#include <hip/hip_runtime.h>
#include <hip/hip_bf16.h>
#include <hip/hip_fp16.h>

#define DEVINL __device__ __forceinline__
typedef __hip_bfloat16 bf16;

typedef __attribute__((ext_vector_type(8))) __bf16 bf16x8;
typedef __attribute__((ext_vector_type(4))) float f32x4;

static constexpr int N_NODES  = 50000;
static constexpr int N_EDGES  = 800000;
static constexpr int N_GRAPHS = 128;
static constexpr float NEG_SLOPE = 0.2f;

// Dual-path input load: isbf=1 -> storage is bf16, else fp32.
DEVINL float ldIn(const void* __restrict__ p, size_t i, int isbf) {
    if (isbf) return __bfloat162float(((const bf16*)p)[i]);
    return ((const float*)p)[i];
}

DEVINL unsigned short f2bf(float f) {
    bf16 b = __float2bfloat16(f);
    return *reinterpret_cast<unsigned short*>(&b);
}

DEVINL unsigned f2hbits(float f) {
    __half h = __float2half(f);
    return (unsigned)*reinterpret_cast<unsigned short*>(&h);
}

DEVINL float hbits2f(unsigned bits) {
    unsigned short us = (unsigned short)bits;
    __half h = *reinterpret_cast<__half*>(&us);
    return __half2float(h);
}

DEVINL float lrelu_exp(float sc) {
    sc = sc > 0.f ? sc : NEG_SLOPE * sc;
    return __expf(sc);
}

// fma two bf16 channels packed in one dword into two f32 accumulators
DEVINL void accw(float w, unsigned wv, float& a0, float& a1) {
    a0 = fmaf(w, __uint_as_float(wv << 16), a0);
    a1 = fmaf(w, __uint_as_float(wv & 0xffff0000u), a1);
}

template<int H>
DEVINL float getse(const uint4& rv, int h) {
    unsigned bits;
    if (H == 4) {
        unsigned w16 = (h & 2) ? rv.z : rv.y;
        bits = (h & 1) ? (w16 >> 16) : (w16 & 0xffffu);
    } else {
        bits = h ? (rv.w >> 16) : (rv.w & 0xffffu);
    }
    return hbits2f(bits);
}

template<int CPL> struct XVT;
template<> struct XVT<8> { using T = uint4; };
template<> struct XVT<4> { using T = uint2; };

// ---------- runtime dtype detection (see round-1 notes) ----------
__global__ void detect_dtype_kernel(const unsigned short* __restrict__ xu,
                                    int* __restrict__ flag)
{
    int t = threadIdx.x;
    int bad = 0;
    for (int i = t; i < 1024; i += 64) {
        unsigned u = xu[2 * i];
        float v = __uint_as_float(u << 16);
        if (!(fabsf(v) <= 1e4f)) bad = 1;
    }
    unsigned long long m = __ballot(bad);
    if (t == 0) *flag = m ? 0 : 1;          // 1 = bf16 storage
}

// ---------- tiny setup: M[d][h] = sum_c We[d, h*64+c] * a_e[h, c] ----------
__global__ void build_M_kernel(const void* __restrict__ We1, const void* __restrict__ ae1,
                               const void* __restrict__ We2, const void* __restrict__ ae2,
                               const int* __restrict__ flagp,
                               float* __restrict__ M1, float* __restrict__ M2)
{
    const int isbf = *flagp;
    int t = threadIdx.x;
    if (t < 64) {
        int d = t >> 2, h = t & 3;
        float s = 0.f;
        for (int c = 0; c < 64; ++c)
            s += ldIn(We1, d * 256 + h * 64 + c, isbf) * ldIn(ae1, h * 64 + c, isbf);
        M1[d * 4 + h] = s;
    }
    if (t < 32) {
        int d = t >> 1, h = t & 1;
        float s = 0.f;
        for (int c = 0; c < 64; ++c)
            s += ldIn(We2, d * 128 + h * 64 + c, isbf) * ldIn(ae2, h * 64 + c, isbf);
        M2[d * 2 + h] = s;
    }
}

// ---------- pack W[K,M] into MFMA B-fragment order ----------
template<int K, int M>
__global__ void build_wfrag_kernel(const void* __restrict__ W, const int* __restrict__ flagp,
                                   bf16* __restrict__ Wfrag)
{
    constexpr int KS = K / 32;
    const int isbf = *flagp;
    int idx = blockIdx.x * 256 + threadIdx.x;
    constexpr int total = (M / 16) * KS * 64 * 8;
    if (idx >= total) return;
    int j    = idx & 7;
    int lane = (idx >> 3) & 63;
    int rem  = idx >> 9;
    int ks   = rem % KS;
    int ct   = rem / KS;
    int k = ks * 32 + (lane >> 4) * 8 + j;
    int n = ct * 16 + (lane & 15);
    Wfrag[idx] = __float2bfloat16(ldIn(W, (size_t)k * M + n, isbf));
}

// ---------- MFMA GEMM + fused node-score epilogue ----------
template<int K, int M, int AMODE, int H>
__global__ __launch_bounds__(256)
void gemm_mfma_kernel(const void* __restrict__ A, const bf16* __restrict__ Wfrag,
                      bf16* __restrict__ C, const int* __restrict__ flagp, int N,
                      const void* __restrict__ a_src, const void* __restrict__ a_dst,
                      float* __restrict__ sA, float* __restrict__ sD)
{
    constexpr int KS = K / 32, CT = M / 16;
    constexpr int LDA = K + 8;
    __shared__ __align__(16) unsigned short Asm[64 * LDA];
    const int isbf = *flagp;
    const int tid  = threadIdx.x;
    const int wave = tid >> 6, lane = tid & 63;
    const int n0 = blockIdx.x * 64;

    for (int i = tid; i < 64 * (K / 8); i += 256) {
        int r  = i / (K / 8);
        int kc = (i % (K / 8)) * 8;
        int n  = n0 + r;
        unsigned short v[8] = {0, 0, 0, 0, 0, 0, 0, 0};
        if (n < N) {
            size_t base = (size_t)n * K + kc;
            if (AMODE == 1 || isbf) {
                *reinterpret_cast<uint4*>(v) =
                    *reinterpret_cast<const uint4*>((const unsigned short*)A + base);
            } else {
                const float* Af = (const float*)A + base;
                float4 f0 = *reinterpret_cast<const float4*>(Af);
                float4 f1 = *reinterpret_cast<const float4*>(Af + 4);
                v[0] = f2bf(f0.x); v[1] = f2bf(f0.y); v[2] = f2bf(f0.z); v[3] = f2bf(f0.w);
                v[4] = f2bf(f1.x); v[5] = f2bf(f1.y); v[6] = f2bf(f1.z); v[7] = f2bf(f1.w);
            }
        }
        *reinterpret_cast<uint4*>(&Asm[r * LDA + kc]) = *reinterpret_cast<uint4*>(v);
    }
    __syncthreads();

    f32x4 acc[CT];
    #pragma unroll
    for (int ct = 0; ct < CT; ++ct) acc[ct] = (f32x4){0.f, 0.f, 0.f, 0.f};

    const int arow  = wave * 16 + (lane & 15);
    const int akoff = (lane >> 4) * 8;
    #pragma unroll
    for (int ks = 0; ks < KS; ++ks) {
        bf16x8 af = *reinterpret_cast<const bf16x8*>(&Asm[arow * LDA + ks * 32 + akoff]);
        #pragma unroll
        for (int ct = 0; ct < CT; ++ct) {
            bf16x8 bfr = *reinterpret_cast<const bf16x8*>(
                &Wfrag[(((size_t)ct * KS + ks) * 64 + lane) * 8]);
            acc[ct] = __builtin_amdgcn_mfma_f32_16x16x32_bf16(af, bfr, acc[ct], 0, 0, 0);
        }
    }

    const int crow0 = n0 + wave * 16 + (lane >> 4) * 4;
    const int ccol  = lane & 15;
    #pragma unroll
    for (int ct = 0; ct < CT; ++ct) {
        #pragma unroll
        for (int r = 0; r < 4; ++r) {
            int row = crow0 + r;
            if (row < N) C[(size_t)row * M + ct * 16 + ccol] = __float2bfloat16(acc[ct][r]);
        }
    }

    // ---- fused attention logits ----
    float psA[4][H], psD[4][H];
    #pragma unroll
    for (int r = 0; r < 4; ++r)
        #pragma unroll
        for (int hh = 0; hh < H; ++hh) { psA[r][hh] = 0.f; psD[r][hh] = 0.f; }
    #pragma unroll
    for (int ct = 0; ct < CT; ++ct) {
        float as = ldIn(a_src, ct * 16 + ccol, isbf);
        float ad = ldIn(a_dst, ct * 16 + ccol, isbf);
        const int hh = ct >> 2;
        #pragma unroll
        for (int r = 0; r < 4; ++r) {
            psA[r][hh] += acc[ct][r] * as;
            psD[r][hh] += acc[ct][r] * ad;
        }
    }
    #pragma unroll
    for (int m = 1; m < 16; m <<= 1) {
        #pragma unroll
        for (int r = 0; r < 4; ++r)
            #pragma unroll
            for (int hh = 0; hh < H; ++hh) {
                psA[r][hh] += __shfl_xor(psA[r][hh], m);
                psD[r][hh] += __shfl_xor(psD[r][hh], m);
            }
    }
    if (ccol == 0) {
        #pragma unroll
        for (int r = 0; r < 4; ++r) {
            int row = crow0 + r;
            if (row < N) {
                #pragma unroll
                for (int hh = 0; hh < H; ++hh) {
                    sA[(size_t)row * H + hh] = psA[r][hh];
                    sD[(size_t)row * H + hh] = psD[r][hh];
                }
            }
        }
    }
}

// ---------- CSR build: count + per-edge stable rank (atomic return) ----------
__global__ void csr_count_kernel(const int* __restrict__ dst, int* __restrict__ cnt,
                                 int* __restrict__ rank)
{
    int e = blockIdx.x * blockDim.x + threadIdx.x;
    if (e >= N_EDGES) return;
    rank[e] = atomicAdd(&cnt[dst[e]], 1);
}

__global__ __launch_bounds__(256)
void scan_sum_kernel(const int* __restrict__ cnt, int* __restrict__ bsum)
{
    __shared__ int sm[256];
    int i = blockIdx.x * 256 + threadIdx.x;
    sm[threadIdx.x] = (i < N_NODES) ? cnt[i] : 0;
    __syncthreads();
    for (int off = 128; off; off >>= 1) {
        if (threadIdx.x < off) sm[threadIdx.x] += sm[threadIdx.x + off];
        __syncthreads();
    }
    if (threadIdx.x == 0) bsum[blockIdx.x] = sm[0];
}

__global__ __launch_bounds__(256)
void scan_off_kernel(int* __restrict__ bsum, int nb)
{
    __shared__ int sm[256];
    int tid = threadIdx.x;
    int v = (tid < nb) ? bsum[tid] : 0;
    sm[tid] = v;
    __syncthreads();
    for (int off = 1; off < 256; off <<= 1) {
        int t = (tid >= off) ? sm[tid - off] : 0;
        __syncthreads();
        sm[tid] += t;
        __syncthreads();
    }
    if (tid < nb) bsum[tid] = sm[tid] - v;
}

__global__ __launch_bounds__(256)
void scan_final_kernel(const int* __restrict__ cnt, const int* __restrict__ bsum,
                       int* __restrict__ row)
{
    __shared__ int sm[256];
    int i = blockIdx.x * 256 + threadIdx.x;
    int tid = threadIdx.x;
    int v = (i < N_NODES) ? cnt[i] : 0;
    sm[tid] = v;
    __syncthreads();
    for (int off = 1; off < 256; off <<= 1) {
        int t = (tid >= off) ? sm[tid - off] : 0;
        __syncthreads();
        sm[tid] += t;
        __syncthreads();
    }
    int excl = sm[tid] - v + bsum[blockIdx.x];
    if (i < N_NODES) row[i] = excl;
    if (i == N_NODES - 1) row[N_NODES] = excl + v;
}

// ---------- scatter (atomic-free): pos = row[d] + rank[e]; one 16-B record ----------
__global__ void csr_scatter_kernel(const int* __restrict__ srcI, const int* __restrict__ dstI,
                                   const void* __restrict__ eattr, const int* __restrict__ flagp,
                                   const float* __restrict__ M1, const float* __restrict__ M2,
                                   const int* __restrict__ row, const int* __restrict__ rank,
                                   uint4* __restrict__ erec)
{
    const int isbf = *flagp;
    int e = blockIdx.x * blockDim.x + threadIdx.x;
    if (e >= N_EDGES) return;
    float attr[16];
    #pragma unroll
    for (int k = 0; k < 16; ++k) attr[k] = ldIn(eattr, (size_t)e * 16 + k, isbf);
    float4 o1 = {0.f, 0.f, 0.f, 0.f};
    float2 o2 = {0.f, 0.f};
    #pragma unroll
    for (int k = 0; k < 16; ++k) {
        o1.x += attr[k] * M1[k * 4 + 0];
        o1.y += attr[k] * M1[k * 4 + 1];
        o1.z += attr[k] * M1[k * 4 + 2];
        o1.w += attr[k] * M1[k * 4 + 3];
        o2.x += attr[k] * M2[k * 2 + 0];
        o2.y += attr[k] * M2[k * 2 + 1];
    }
    int pos = row[dstI[e]] + rank[e];
    uint4 rec;
    rec.x = (unsigned)srcI[e];
    rec.y = f2hbits(o1.x) | (f2hbits(o1.y) << 16);
    rec.z = f2hbits(o1.z) | (f2hbits(o1.w) << 16);
    rec.w = f2hbits(o2.x) | (f2hbits(o2.y) << 16);
    erec[pos] = rec;
}

// ---------- fused score+softmax+aggregate: one wave per dst, TWO edges per wave ----
// 32 lanes per edge row (sub = lane>>5 picks the edge of the pair); CPL channels
// per lane. Replicated scalar work (se extract, exp, score adds) now covers 2
// edges per wave-instruction. Cross-half shfl_xor(32) reduce at the end.
// LAYER 1 (H=4): out = relu(agg + b1) -> bf16 h1[N,256]
// LAYER 2 (H=2): out = mean_heads(agg) + b2 -> fp32 h2[N,64]
template<int H, int LAYER>
__global__ __launch_bounds__(256)
void agg_fused_kernel(const int* __restrict__ row, const uint4* __restrict__ erec,
                      const bf16* __restrict__ xs,
                      const float* __restrict__ sA, const float* __restrict__ sD,
                      const void* __restrict__ bias,
                      const int* __restrict__ flagp, void* __restrict__ out)
{
    constexpr int CPL = (H * 64) / 32;                  // channels per lane (8 / 4)
    using XV = typename XVT<CPL>::T;
    const int isbf = *flagp;
    int dv = (blockIdx.x * 256 + threadIdx.x) >> 6;
    const int d = __builtin_amdgcn_readfirstlane(dv);   // wave-uniform -> scalar loads
    const int lane = threadIdx.x & 63;
    if (d >= N_NODES) return;
    const int sub = lane >> 5;                          // which edge of the pair
    const int sl  = lane & 31;                          // slot within the row
    const int h = (sl * CPL) >> 6;                      // this lane's head
    const unsigned short* xsu = (const unsigned short*)xs;
    const float sDv = sD[(size_t)d * H + h];
    const float sAd = sA[(size_t)d * H + h];

    float acc[CPL];
    #pragma unroll
    for (int i = 0; i < CPL; ++i) acc[i] = 0.f;
    float den = 0.f, seSum = 0.f;

    const int b = row[d], eend = row[d + 1];
    const int nb8 = (eend - b) & ~7;

    for (int j0 = b; j0 < b + nb8; j0 += 8) {           // 4 pairs = 8 edges / iter
        uint4 rv[4];
        int   s[4];
        XV    xv[4];
        float sa[4], se[4];
        #pragma unroll
        for (int u = 0; u < 4; ++u) rv[u] = erec[j0 + 2 * u + sub];
        #pragma unroll
        for (int u = 0; u < 4; ++u) s[u] = (int)rv[u].x;
        #pragma unroll
        for (int u = 0; u < 4; ++u)
            xv[u] = *reinterpret_cast<const XV*>(&xsu[(size_t)s[u] * (H * 64) + sl * CPL]);
        #pragma unroll
        for (int u = 0; u < 4; ++u) sa[u] = sA[(size_t)s[u] * H + h];
        #pragma unroll
        for (int u = 0; u < 4; ++u) se[u] = getse<H>(rv[u], h);
        #pragma unroll
        for (int u = 0; u < 4; ++u) {
            float w = lrelu_exp(sa[u] + sDv + se[u]);
            seSum += se[u];
            den += w;
            const unsigned* wv = reinterpret_cast<const unsigned*>(&xv[u]);
            #pragma unroll
            for (int p = 0; p < CPL / 2; ++p) accw(w, wv[p], acc[2 * p], acc[2 * p + 1]);
        }
    }
    for (int j0 = b + nb8; j0 < eend; j0 += 2) {        // masked tail pairs
        int jj = j0 + sub;
        bool valid = jj < eend;
        int jc = valid ? jj : (eend - 1);
        uint4 rv = erec[jc];
        int s = (int)rv.x;
        float se = getse<H>(rv, h);
        float sa = sA[(size_t)s * H + h];
        XV xv = *reinterpret_cast<const XV*>(&xsu[(size_t)s * (H * 64) + sl * CPL]);
        float w = valid ? lrelu_exp(sa + sDv + se) : 0.f;
        seSum += valid ? se : 0.f;
        den += w;
        const unsigned* wv = reinterpret_cast<const unsigned*>(&xv);
        #pragma unroll
        for (int p = 0; p < CPL / 2; ++p) accw(w, wv[p], acc[2 * p], acc[2 * p + 1]);
    }

    // cross-half reduce (sub0 holds even edges, sub1 odd; same channels/head)
    #pragma unroll
    for (int i = 0; i < CPL; ++i) acc[i] += __shfl_xor(acc[i], 32);
    den   += __shfl_xor(den, 32);
    seSum += __shfl_xor(seSum, 32);

    // self loop: attr = mean of incident edge attrs -> se_self = seSum/cnt
    {
        const int cntv = eend - b;
        const float seM = seSum / fmaxf((float)cntv, 1.f);
        const float wS = lrelu_exp(sAd + sDv + seM);
        XV xv = *reinterpret_cast<const XV*>(&xsu[(size_t)d * (H * 64) + sl * CPL]);
        den += wS;
        const unsigned* wv = reinterpret_cast<const unsigned*>(&xv);
        #pragma unroll
        for (int p = 0; p < CPL / 2; ++p) accw(wS, wv[p], acc[2 * p], acc[2 * p + 1]);
    }

    const float rden = 1.f / (den + 1e-16f);
    if (LAYER == 1) {
        if (sub == 0) {
            unsigned o[CPL / 2];
            #pragma unroll
            for (int p = 0; p < CPL / 2; ++p) {
                float v0 = acc[2 * p] * rden + ldIn(bias, sl * CPL + 2 * p, isbf);
                float v1 = acc[2 * p + 1] * rden + ldIn(bias, sl * CPL + 2 * p + 1, isbf);
                v0 = v0 > 0.f ? v0 : 0.f;
                v1 = v1 > 0.f ? v1 : 0.f;
                o[p] = (unsigned)f2bf(v0) | ((unsigned)f2bf(v1) << 16);
            }
            *reinterpret_cast<uint4*>(&((unsigned short*)out)[(size_t)d * (H * 64) + sl * CPL]) =
                *reinterpret_cast<uint4*>(o);
        }
    } else {
        // H=2: lane sl<16 holds head0 chans sl*4..+3; partner sl+16 holds head1
        float v[CPL], p[CPL];
        #pragma unroll
        for (int i = 0; i < CPL; ++i) {
            v[i] = acc[i] * rden;
            p[i] = __shfl_xor(v[i], 16);
        }
        if (lane < 16) {
            float4 o;
            o.x = 0.5f * (v[0] + p[0]) + ldIn(bias, sl * 4 + 0, isbf);
            o.y = 0.5f * (v[1] + p[1]) + ldIn(bias, sl * 4 + 1, isbf);
            o.z = 0.5f * (v[2] + p[2]) + ldIn(bias, sl * 4 + 2, isbf);
            o.w = 0.5f * (v[3] + p[3]) + ldIn(bias, sl * 4 + 3, isbf);
            *reinterpret_cast<float4*>(&((float*)out)[(size_t)d * 64 + sl * 4]) = o;
        }
    }
}

// ---------- pooling ----------
__global__ __launch_bounds__(256)
void pool_max_kernel(const float* __restrict__ h2, const int* __restrict__ batch,
                     float* __restrict__ g)
{
    int gi = blockIdx.x;
    int lo = 0, hi = N_NODES;
    while (lo < hi) { int mid = (lo + hi) >> 1; if (batch[mid] < gi) lo = mid + 1; else hi = mid; }
    int start = lo;
    lo = start; hi = N_NODES;
    while (lo < hi) { int mid = (lo + hi) >> 1; if (batch[mid] < gi + 1) lo = mid + 1; else hi = mid; }
    int end = lo;
    int c = threadIdx.x & 63, chunk = threadIdx.x >> 6;
    float m = -INFINITY;
    for (int n = start + chunk; n < end; n += 4) m = fmaxf(m, h2[(size_t)n * 64 + c]);
    __shared__ float sm[256];
    sm[threadIdx.x] = m;
    __syncthreads();
    if (threadIdx.x < 64) {
        m = fmaxf(fmaxf(sm[threadIdx.x], sm[threadIdx.x + 64]),
                  fmaxf(sm[threadIdx.x + 128], sm[threadIdx.x + 192]));
        g[gi * 64 + threadIdx.x] = m;
    }
}

// ---------- readout ----------
__global__ void readout_kernel(const float* __restrict__ g, const void* __restrict__ Wr,
                               const void* __restrict__ br, const int* __restrict__ flagp,
                               void* __restrict__ out)
{
    const int isbf = *flagp;
    int gi = blockIdx.x;
    int lane = threadIdx.x;
    float p = g[gi * 64 + lane] * ldIn(Wr, lane, isbf);
    for (int off = 32; off; off >>= 1) p += __shfl_down(p, off);
    if (lane == 0) {
        float r = p + ldIn(br, 0, isbf);
        if (isbf) ((bf16*)out)[gi] = __float2bfloat16(r);
        else      ((float*)out)[gi] = r;
    }
}

extern "C" void kernel_launch(void* const* d_in, const int* in_sizes, int n_in,
                              void* d_out, int out_size, void* d_ws, size_t ws_size,
                              hipStream_t stream)
{
    const void* x     = d_in[0];
    const void* ea    = d_in[1];
    const int*  eidx  = (const int*)d_in[2];
    const int*  batch = (const int*)d_in[3];
    const void* W1  = d_in[4];
    const void* as1 = d_in[5];
    const void* ad1 = d_in[6];
    const void* We1 = d_in[7];
    const void* ae1 = d_in[8];
    const void* b1  = d_in[9];
    const void* W2  = d_in[10];
    const void* as2 = d_in[11];
    const void* ad2 = d_in[12];
    const void* We2 = d_in[13];
    const void* ae2 = d_in[14];
    const void* b2  = d_in[15];
    const void* Wr  = d_in[16];
    const void* br  = d_in[17];

    const int* srcI = eidx;
    const int* dstI = eidx + N_EDGES;

    // ---- workspace layout (float-index offsets), peak ~70 MB ----
    float* ws    = (float*)d_ws;
    bf16*  xs    = (bf16*)ws;                     // [0, 6.4M): N*256 bf16 (L2: N*128)
    bf16*  h1    = (bf16*)(ws + 6400000);         // N*256 bf16 -> [6.4M, 12.8M)
    float* h2    = ws + 6400000;                  // N*64 fp32 overlay (h1 dead after gemm2)
    uint4* erec  = (uint4*)(ws + 12800000);       // E 16-B records -> [12.8M, 16M)
    float* sA1   = ws + 16000000;                 // N*4
    float* sD1   = ws + 16200000;                 // N*4
    float* sA2   = ws + 16400000;                 // N*2
    float* sD2   = ws + 16500000;                 // N*2
    int*   ib    = (int*)(ws + 16600000);
    int*   row    = ib;                           // N+1 (pad 50016)
    int*   cnt    = ib + 50016;                   // N (pad 50016)
    int*   bsum   = ib + 100032;                  // 256 (pad 352)
    int*   rank   = ib + 100384;                  // E
    float* misc  = ws + 16600000 + 900384;
    int*   flag  = (int*)misc;                    // 1
    float* M1    = misc + 16;                     // 64
    float* M2    = misc + 80;                     // 32
    float* gpool = misc + 112;                    // 128*64
    bf16*  wf1   = (bf16*)(misc + 8320);          // 32768 bf16
    bf16*  wf2   = (bf16*)(misc + 8320 + 16384);  // 32768 bf16

    hipMemsetAsync(cnt, 0, N_NODES * sizeof(int), stream);

    detect_dtype_kernel<<<1, 64, 0, stream>>>((const unsigned short*)x, flag);
    build_M_kernel<<<1, 64, 0, stream>>>(We1, ae1, We2, ae2, flag, M1, M2);
    build_wfrag_kernel<128, 256><<<128, 256, 0, stream>>>(W1, flag, wf1);
    build_wfrag_kernel<256, 128><<<128, 256, 0, stream>>>(W2, flag, wf2);

    // ----- CSR over dst (parallel scan) + atomic-free packed-record scatter -----
    const int NB = (N_NODES + 255) / 256;         // 196
    csr_count_kernel<<<(N_EDGES + 255) / 256, 256, 0, stream>>>(dstI, cnt, rank);
    scan_sum_kernel<<<NB, 256, 0, stream>>>(cnt, bsum);
    scan_off_kernel<<<1, 256, 0, stream>>>(bsum, NB);
    scan_final_kernel<<<NB, 256, 0, stream>>>(cnt, bsum, row);
    csr_scatter_kernel<<<(N_EDGES + 255) / 256, 256, 0, stream>>>(
        srcI, dstI, ea, flag, M1, M2, row, rank, erec);

    const int GB = (N_NODES + 63) / 64;           // 782 row-blocks

    // ----- layer 1 (H=4, concat); node scores fused into GEMM epilogue -----
    gemm_mfma_kernel<128, 256, 0, 4><<<GB, 256, 0, stream>>>(
        x, wf1, xs, flag, N_NODES, as1, ad1, sA1, sD1);
    agg_fused_kernel<4, 1><<<(N_NODES + 3) / 4, 256, 0, stream>>>(
        row, erec, xs, sA1, sD1, b1, flag, h1);

    // ----- layer 2 (H=2, mean) -----
    gemm_mfma_kernel<256, 128, 1, 2><<<GB, 256, 0, stream>>>(
        h1, wf2, xs, flag, N_NODES, as2, ad2, sA2, sD2);
    agg_fused_kernel<2, 2><<<(N_NODES + 3) / 4, 256, 0, stream>>>(
        row, erec, xs, sA2, sD2, b2, flag, h2);

    // ----- pool + readout -----
    pool_max_kernel<<<N_GRAPHS, 256, 0, stream>>>(h2, batch, gpool);
    readout_kernel<<<N_GRAPHS, 64, 0, stream>>>(gpool, Wr, br, flag, d_out);
}